// Round 3
// baseline (541.754 us; speedup 1.0000x reference)
//
#include <hip/hip_runtime.h>
#include <hip/hip_cooperative_groups.h>
#include <math.h>

namespace cg = cooperative_groups;

#define B 4
#define NPTS 300000
#define G 15
#define G3 3375
#define PAIR_FLOATS (4*G3)       // 13500 floats: one (b,set) grid, 4 channels
#define SCENE_FLOATS (B*12*G3)   // 162000

__device__ __forceinline__ float eluf(float v) {
    return v > 0.0f ? v : __expf(v) - 1.0f;
}

// ---------------------------------------------------------------------------
// Phase A: pure MLP. One point per thread, NO loop, NO atomics, NO LDS.
// Weights consumed straight from the scalar cache (24 VGPR codegen).
// Streams o[4] + cell to workspace.
// grid: (ceil(m/256), B, 3)
// ---------------------------------------------------------------------------
__global__ __launch_bounds__(256)
void mlp_kernel(const float* __restrict__ P0,   // inputs  (set 0)
                const float* __restrict__ P1,   // goals   (set 1)
                const float* __restrict__ P2,   // backgrounds (set 2)
                const float* __restrict__ W1, const float* __restrict__ b1,
                const float* __restrict__ W2, const float* __restrict__ b2,
                const float* __restrict__ W3, const float* __restrict__ b3,
                float4* __restrict__ vals, int* __restrict__ cells,
                int s0, int m)
{
    int b   = blockIdx.y;
    int set = blockIdx.z;
    int i   = blockIdx.x * 256 + threadIdx.x;
    if (i >= m) return;
    const float* P = (set == 0) ? P0 : ((set == 1) ? P1 : P2);

    const float* p = P + ((size_t)b * NPTS + (size_t)(s0 + i)) * 3;
    float px = p[0], py = p[1], pz = p[2];

    const float HI = 14.9999f;  // GZ - 1e-4
    float cx = floorf(fminf(fmaxf(px, 0.0f), HI));
    float cy = floorf(fminf(fmaxf(py, 0.0f), HI));
    float cz = floorf(fminf(fmaxf(pz, 0.0f), HI));

    float x[12];
    x[0] = px - (cx + 0.5f); x[1] = py - (cy + 0.5f); x[2] = pz - (cz + 0.5f);
    x[3] = px - cx;          x[4] = py - cy;          x[5] = pz - cz;
    x[6] = px - (cx + 1.0f); x[7] = py - (cy + 1.0f); x[8] = pz - (cz + 1.0f);
    x[9]  = sqrtf(x[0]*x[0] + x[1]*x[1] + x[2]*x[2]);
    x[10] = sqrtf(x[3]*x[3] + x[4]*x[4] + x[5]*x[5]);
    x[11] = sqrtf(x[6]*x[6] + x[7]*x[7] + x[8]*x[8]);

    float h1[16];
#pragma unroll
    for (int j = 0; j < 16; ++j) {
        float s = b1[j];
#pragma unroll
        for (int k = 0; k < 12; ++k) s = fmaf(x[k], W1[k*16 + j], s);
        h1[j] = eluf(s);
    }
    float h2[16];
#pragma unroll
    for (int j = 0; j < 16; ++j) {
        float s = b2[j];
#pragma unroll
        for (int k = 0; k < 16; ++k) s = fmaf(h1[k], W2[k*16 + j], s);
        h2[j] = eluf(s);
    }
    float o[4];
#pragma unroll
    for (int j = 0; j < 4; ++j) {
        float s = b3[j];
#pragma unroll
        for (int k = 0; k < 16; ++k) s = fmaf(h2[k], W3[k*4 + j], s);
        o[j] = s;
    }

    int cell = (((int)cx) * G + (int)cy) * G + (int)cz;
    int pair = b * 3 + set;
    vals [(size_t)pair * m + i] = make_float4(o[0], o[1], o[2], o[3]);
    cells[(size_t)pair * m + i] = cell;
}

// ---------------------------------------------------------------------------
// Phase B: scatter-max into a PRIVATE LDS grid (54 KB), flush with plain
// stores into this block's replica. For segment > 0, re-load own replica.
// grid: (K, B, 3); block 256.
// ---------------------------------------------------------------------------
__global__ __launch_bounds__(256)
void scatter_kernel(const float4* __restrict__ vals,
                    const int* __restrict__ cells,
                    float* __restrict__ scenesR, int K, int m, int carry)
{
    __shared__ unsigned sg[PAIR_FLOATS];   // uint-ordered positive floats

    int rep = blockIdx.x;
    int b   = blockIdx.y;
    int set = blockIdx.z;
    int pair = b * 3 + set;
    float* myrep = scenesR + ((size_t)pair * K + rep) * PAIR_FLOATS;

    if (carry) {
        for (int i = threadIdx.x; i < PAIR_FLOATS; i += 256)
            sg[i] = __float_as_uint(myrep[i]);     // values are >= 0
    } else {
        for (int i = threadIdx.x; i < PAIR_FLOATS; i += 256)
            sg[i] = 0u;
    }
    __syncthreads();

    int chunk = (m + K - 1) / K;
    int start = rep * chunk;
    int end   = min(m, start + chunk);
    const float4* v = vals  + (size_t)pair * m;
    const int*    c = cells + (size_t)pair * m;

    for (int i = start + (int)threadIdx.x; i < end; i += 256) {
        float4 o = v[i];
        int cell = c[i];
        if (o.x > 0.0f) atomicMax(&sg[          cell], __float_as_uint(o.x));
        if (o.y > 0.0f) atomicMax(&sg[    G3 + cell], __float_as_uint(o.y));
        if (o.z > 0.0f) atomicMax(&sg[2 * G3 + cell], __float_as_uint(o.z));
        if (o.w > 0.0f) atomicMax(&sg[3 * G3 + cell], __float_as_uint(o.w));
    }
    __syncthreads();

    for (int i = threadIdx.x; i < PAIR_FLOATS; i += 256)
        myrep[i] = __uint_as_float(sg[i]);
}

// ---------------------------------------------------------------------------
// Fused tail: reduce replicas -> scenes -> conv1 -> 6x(BN+ELU+conv) -> BN+ELU
// Single cooperative kernel, 256 blocks x 256 threads (1 block/CU).
// Each conv layer is ~0.2us of math on L2-resident 64KB tensors; the old
// 8-launch chain was ~99% launch/drain overhead. grid.sync() replaces it.
// ---------------------------------------------------------------------------
__global__ __launch_bounds__(256)
void conv_chain_kernel(const float* __restrict__ scenesR, float* __restrict__ scenes,
                       const float* __restrict__ c1w,  // [8,12,125]
                       const float* __restrict__ c1b,  // [8]
                       const float* __restrict__ csw,  // [6,8,8,125]
                       const float* __restrict__ csb,  // [6,8]
                       const float* __restrict__ bn1_g, const float* __restrict__ bn1_b,
                       const float* __restrict__ bns_g, const float* __restrict__ bns_b,
                       float* __restrict__ yA, float* __restrict__ yB,
                       float* __restrict__ stats, float* __restrict__ outp, int K)
{
    cg::grid_group gridg = cg::this_grid();

    __shared__ float slab[8 * 5 * 144];   // [ci][kd][12][12], zero-padded
    __shared__ float sscale[8], sshift[8];
    __shared__ float sred[256];

    int bx  = blockIdx.x;
    int tid = threadIdx.x;
    int gtid = bx * 256 + tid;
    int od = bx & 7, co = (bx >> 3) & 7, b = bx >> 6;

    // ---- phase 0: max-reduce K replicas per pair -> scenes -----------------
    for (int t = gtid; t < SCENE_FLOATS; t += 256 * 256) {
        int pair = t / PAIR_FLOATS;
        int j    = t - pair * PAIR_FLOATS;
        const float* src = scenesR + (size_t)pair * K * PAIR_FLOATS + j;
        float mx = 0.0f;
        for (int r = 0; r < K; ++r)
            mx = fmaxf(mx, src[(size_t)r * PAIR_FLOATS]);
        scenes[t] = mx;
    }
    gridg.sync();

    // ---- phase 1: conv1 (stride 2, pad 2): scenes -> yA, stats[0:16] -------
    {
        int ow = tid & 7, oh = (tid >> 3) & 7, ciq = tid >> 6;
        float s = 0.0f;
        for (int cin = 0; cin < 3; ++cin) {
            int ci = ciq * 3 + cin;
            const float* sc = scenes + (size_t)(b * 12 + ci) * G3;
            const float* wc = c1w + (size_t)(co * 12 + ci) * 125;
#pragma unroll
            for (int kd = 0; kd < 5; ++kd) {
                int id = od * 2 - 2 + kd;
                if ((unsigned)id >= (unsigned)G) continue;   // block-uniform
#pragma unroll
                for (int kh = 0; kh < 5; ++kh) {
                    int ih = oh * 2 - 2 + kh;
                    bool hok = (unsigned)ih < (unsigned)G;
#pragma unroll
                    for (int kw = 0; kw < 5; ++kw) {
                        int iw = ow * 2 - 2 + kw;
                        if (hok && (unsigned)iw < (unsigned)G)
                            s = fmaf(sc[(id * G + ih) * G + iw], wc[kd*25 + kh*5 + kw], s);
                    }
                }
            }
        }
        sred[tid] = s;
        __syncthreads();
        if (tid < 64) {
            float tot = sred[tid] + sred[64+tid] + sred[128+tid] + sred[192+tid] + c1b[co];
            yA[(size_t)(b * 8 + co) * 512 + od * 64 + tid] = tot;
            float sum = tot, sq = tot * tot;
#pragma unroll
            for (int o = 32; o > 0; o >>= 1) {
                sum += __shfl_down(sum, o, 64);
                sq  += __shfl_down(sq,  o, 64);
            }
            if (tid == 0) { atomicAdd(&stats[co], sum); atomicAdd(&stats[8 + co], sq); }
        }
    }
    gridg.sync();

    // ---- phases 2..7: BN(prev stats)+ELU on the fly, then 5^3 conv ---------
    float* cur = yA;
    float* nxt = yB;
    for (int layer = 0; layer < 6; ++layer) {
        const float* g        = (layer == 0) ? bn1_g : (bns_g + (layer - 1) * 8);
        const float* bet      = (layer == 0) ? bn1_b : (bns_b + (layer - 1) * 8);
        const float* stats_in = stats + layer * 16;
        float*      stats_out = stats + (layer + 1) * 16;
        const float* w        = csw + (size_t)layer * 8000;
        const float* bias     = csb + layer * 8;

        if (tid < 8) {
            float S = stats_in[tid], Q = stats_in[8 + tid];
            float m  = S * (1.0f / 2048.0f);
            float vv = Q * (1.0f / 2048.0f) - m * m;
            float rs = rsqrtf(vv + 1e-5f);
            float sc = g[tid] * rs;
            sscale[tid] = sc;
            sshift[tid] = bet[tid] - m * sc;
        }
        __syncthreads();

        for (int s = tid; s < 5760; s += 256) {
            int ci = s / 720; int r = s % 720;
            int kd = r / 144; int r2 = r % 144;
            int ph = r2 / 12, pw = r2 % 12;
            int id = od - 2 + kd, ih = ph - 2, iw = pw - 2;
            float v = 0.0f;
            if ((unsigned)id < 8u && (unsigned)ih < 8u && (unsigned)iw < 8u) {
                float raw = cur[(size_t)(b * 8 + ci) * 512 + id * 64 + ih * 8 + iw];
                float t = fmaf(raw, sscale[ci], sshift[ci]);
                v = t > 0.0f ? t : __expf(t) - 1.0f;
            }
            slab[s] = v;
        }
        __syncthreads();

        int ow = tid & 7, oh = (tid >> 3) & 7, ciq = tid >> 6;
        float s = 0.0f;
#pragma unroll
        for (int c2 = 0; c2 < 2; ++c2) {
            int ci = ciq * 2 + c2;
            const float* sl = slab + ci * 720;
            const float* wc = w + (size_t)(co * 8 + ci) * 125;
#pragma unroll
            for (int kd = 0; kd < 5; ++kd) {
#pragma unroll
                for (int kh = 0; kh < 5; ++kh) {
                    const float* row = sl + kd * 144 + (oh + kh) * 12 + ow;
                    const float* wr = wc + kd * 25 + kh * 5;
#pragma unroll
                    for (int kw = 0; kw < 5; ++kw) s = fmaf(row[kw], wr[kw], s);
                }
            }
        }
        sred[tid] = s;
        __syncthreads();
        if (tid < 64) {
            float tot = sred[tid] + sred[64+tid] + sred[128+tid] + sred[192+tid] + bias[co];
            nxt[(size_t)(b * 8 + co) * 512 + od * 64 + tid] = tot;
            float sum = tot, sq = tot * tot;
#pragma unroll
            for (int o = 32; o > 0; o >>= 1) {
                sum += __shfl_down(sum, o, 64);
                sq  += __shfl_down(sq,  o, 64);
            }
            if (tid == 0) { atomicAdd(&stats_out[co], sum); atomicAdd(&stats_out[8 + co], sq); }
        }
        gridg.sync();
        float* tmp = cur; cur = nxt; nxt = tmp;
        __syncthreads();   // slab reuse safety within block
    }

    // ---- phase 8: final BN + ELU -> outp -----------------------------------
    if (gtid < 16384) {
        const float* stats_in = stats + 6 * 16;
        int c = (gtid >> 9) & 7;
        float S = stats_in[c], Q = stats_in[8 + c];
        float m  = S * (1.0f / 2048.0f);
        float vv = Q * (1.0f / 2048.0f) - m * m;
        float rs = rsqrtf(vv + 1e-5f);
        float sc = (bns_g + 5 * 8)[c] * rs;
        float sh = (bns_b + 5 * 8)[c] - m * sc;
        float t = fmaf(cur[gtid], sc, sh);
        outp[gtid] = t > 0.0f ? t : __expf(t) - 1.0f;
    }
}

// ---------------------------------------------------------------------------
extern "C" void kernel_launch(void* const* d_in, const int* in_sizes, int n_in,
                              void* d_out, int out_size, void* d_ws, size_t ws_size,
                              hipStream_t stream)
{
    const float* goals       = (const float*)d_in[0];
    const float* inputs      = (const float*)d_in[1];
    const float* backgrounds = (const float*)d_in[2];
    const float* W1 = (const float*)d_in[3];
    const float* b1 = (const float*)d_in[4];
    const float* W2 = (const float*)d_in[5];
    const float* b2 = (const float*)d_in[6];
    const float* W3 = (const float*)d_in[7];
    const float* b3 = (const float*)d_in[8];
    const float* conv1_w = (const float*)d_in[9];
    const float* conv1_b = (const float*)d_in[10];
    const float* bn1_g   = (const float*)d_in[11];
    const float* bn1_b   = (const float*)d_in[12];
    const float* convs_w = (const float*)d_in[13];
    const float* convs_b = (const float*)d_in[14];
    const float* bns_g   = (const float*)d_in[15];
    const float* bns_b   = (const float*)d_in[16];

    // --- pick (K replicas, S segments) to fit the workspace -----------------
    long ws_floats = (long)(ws_size / 4);
    long fixed = SCENE_FLOATS + 2L * 16384 + 112;
    static const int plans[][2] = {
        {42,1},{42,2},{42,4},{24,4},{21,6},{16,8},{8,12},{4,16},{2,32},{1,64}};
    int K = 1, S = 64;
    for (int pi = 0; pi < 10; ++pi) {
        int pk = plans[pi][0], ps = plans[pi][1];
        long mseg = (NPTS + ps - 1) / ps;
        long need = 60L * mseg + (long)pk * SCENE_FLOATS + fixed;
        if (need <= ws_floats) { K = pk; S = ps; break; }
    }
    int Mseg = (NPTS + S - 1) / S;

    float*  wsp     = (float*)d_ws;
    float4* vals    = (float4*)wsp;                          // 12*Mseg float4
    int*    cells   = (int*)(wsp + 48L * Mseg);              // 12*Mseg ints
    float*  scenesR = wsp + 60L * Mseg;                      // K * SCENE_FLOATS
    float*  scenes  = scenesR + (size_t)K * SCENE_FLOATS;    // 162000
    float*  yA      = scenes + SCENE_FLOATS;                 // 16384
    float*  yB      = yA + 16384;                            // 16384
    float*  stats   = yB + 16384;                            // 7*16 floats

    hipMemsetAsync(stats, 0, 7 * 16 * sizeof(float), stream);

    for (int s = 0; s < S; ++s) {
        int s0 = s * Mseg;
        int m  = min(Mseg, NPTS - s0);
        dim3 agrid((m + 255) / 256, B, 3);
        mlp_kernel<<<agrid, 256, 0, stream>>>(inputs, goals, backgrounds,
                                              W1, b1, W2, b2, W3, b3,
                                              vals, cells, s0, m);
        dim3 bgrid(K, B, 3);
        scatter_kernel<<<bgrid, 256, 0, stream>>>(vals, cells, scenesR, K, m,
                                                  s > 0 ? 1 : 0);
    }

    float* outp = (float*)d_out;
    void* cargs[] = {
        (void*)&scenesR, (void*)&scenes, (void*)&conv1_w, (void*)&conv1_b,
        (void*)&convs_w, (void*)&convs_b, (void*)&bn1_g, (void*)&bn1_b,
        (void*)&bns_g, (void*)&bns_b, (void*)&yA, (void*)&yB,
        (void*)&stats, (void*)&outp, (void*)&K };
    hipLaunchCooperativeKernel((void*)conv_chain_kernel, dim3(256), dim3(256),
                               cargs, 0, stream);
}

// Round 4
// 477.205 us; speedup vs baseline: 1.1353x; 1.1353x over previous
//
#include <hip/hip_runtime.h>
#include <math.h>

#define B 4
#define NPTS 300000
#define G 15
#define G3 3375
#define PAIR_FLOATS (4*G3)       // 13500 floats: one (b,set) grid, 4 channels
#define SCENE_FLOATS (B*12*G3)   // 162000

__device__ __forceinline__ float eluf(float v) {
    return v > 0.0f ? v : __expf(v) - 1.0f;
}

// ---------------------------------------------------------------------------
// Phase A: pure MLP. One point per thread, NO loop, NO atomics, NO LDS.
// Weights consumed straight from the scalar cache (24 VGPR codegen).
// ---------------------------------------------------------------------------
__global__ __launch_bounds__(256)
void mlp_kernel(const float* __restrict__ P0,   // inputs  (set 0)
                const float* __restrict__ P1,   // goals   (set 1)
                const float* __restrict__ P2,   // backgrounds (set 2)
                const float* __restrict__ W1, const float* __restrict__ b1,
                const float* __restrict__ W2, const float* __restrict__ b2,
                const float* __restrict__ W3, const float* __restrict__ b3,
                float4* __restrict__ vals, int* __restrict__ cells,
                int s0, int m)
{
    int b   = blockIdx.y;
    int set = blockIdx.z;
    int i   = blockIdx.x * 256 + threadIdx.x;
    if (i >= m) return;
    const float* P = (set == 0) ? P0 : ((set == 1) ? P1 : P2);

    const float* p = P + ((size_t)b * NPTS + (size_t)(s0 + i)) * 3;
    float px = p[0], py = p[1], pz = p[2];

    const float HI = 14.9999f;  // GZ - 1e-4
    float cx = floorf(fminf(fmaxf(px, 0.0f), HI));
    float cy = floorf(fminf(fmaxf(py, 0.0f), HI));
    float cz = floorf(fminf(fmaxf(pz, 0.0f), HI));

    float x[12];
    x[0] = px - (cx + 0.5f); x[1] = py - (cy + 0.5f); x[2] = pz - (cz + 0.5f);
    x[3] = px - cx;          x[4] = py - cy;          x[5] = pz - cz;
    x[6] = px - (cx + 1.0f); x[7] = py - (cy + 1.0f); x[8] = pz - (cz + 1.0f);
    x[9]  = sqrtf(x[0]*x[0] + x[1]*x[1] + x[2]*x[2]);
    x[10] = sqrtf(x[3]*x[3] + x[4]*x[4] + x[5]*x[5]);
    x[11] = sqrtf(x[6]*x[6] + x[7]*x[7] + x[8]*x[8]);

    float h1[16];
#pragma unroll
    for (int j = 0; j < 16; ++j) {
        float s = b1[j];
#pragma unroll
        for (int k = 0; k < 12; ++k) s = fmaf(x[k], W1[k*16 + j], s);
        h1[j] = eluf(s);
    }
    float h2[16];
#pragma unroll
    for (int j = 0; j < 16; ++j) {
        float s = b2[j];
#pragma unroll
        for (int k = 0; k < 16; ++k) s = fmaf(h1[k], W2[k*16 + j], s);
        h2[j] = eluf(s);
    }
    float o[4];
#pragma unroll
    for (int j = 0; j < 4; ++j) {
        float s = b3[j];
#pragma unroll
        for (int k = 0; k < 16; ++k) s = fmaf(h2[k], W3[k*4 + j], s);
        o[j] = s;
    }

    int cell = (((int)cx) * G + (int)cy) * G + (int)cz;
    int pair = b * 3 + set;
    vals [(size_t)pair * m + i] = make_float4(o[0], o[1], o[2], o[3]);
    cells[(size_t)pair * m + i] = cell;
}

// ---------------------------------------------------------------------------
// Phase B: scatter-max into a PRIVATE LDS grid (54 KB), flush with plain
// stores into this block's replica. 512 threads (16 waves/CU at 2 blocks/CU)
// for latency hiding of the vals stream.
// grid: (K, B, 3); block 512.
// ---------------------------------------------------------------------------
__global__ __launch_bounds__(512)
void scatter_kernel(const float4* __restrict__ vals,
                    const int* __restrict__ cells,
                    float* __restrict__ scenesR, int K, int m, int carry)
{
    __shared__ unsigned sg[PAIR_FLOATS];   // uint-ordered positive floats

    int rep = blockIdx.x;
    int b   = blockIdx.y;
    int set = blockIdx.z;
    int pair = b * 3 + set;
    float* myrep = scenesR + ((size_t)pair * K + rep) * PAIR_FLOATS;

    if (carry) {
        for (int i = threadIdx.x; i < PAIR_FLOATS; i += 512)
            sg[i] = __float_as_uint(myrep[i]);     // values are >= 0
    } else {
        for (int i = threadIdx.x; i < PAIR_FLOATS; i += 512)
            sg[i] = 0u;
    }
    __syncthreads();

    int chunk = (m + K - 1) / K;
    int start = rep * chunk;
    int end   = min(m, start + chunk);
    const float4* v = vals  + (size_t)pair * m;
    const int*    c = cells + (size_t)pair * m;

    for (int i = start + (int)threadIdx.x; i < end; i += 512) {
        float4 o = v[i];
        int cell = c[i];
        if (o.x > 0.0f) atomicMax(&sg[          cell], __float_as_uint(o.x));
        if (o.y > 0.0f) atomicMax(&sg[    G3 + cell], __float_as_uint(o.y));
        if (o.z > 0.0f) atomicMax(&sg[2 * G3 + cell], __float_as_uint(o.z));
        if (o.w > 0.0f) atomicMax(&sg[3 * G3 + cell], __float_as_uint(o.w));
    }
    __syncthreads();

    for (int i = threadIdx.x; i < PAIR_FLOATS; i += 512)
        myrep[i] = __uint_as_float(sg[i]);
}

// ---------------------------------------------------------------------------
// max-reduce K replicas per pair -> scenes [B,12,G3]
// ---------------------------------------------------------------------------
__global__ __launch_bounds__(256)
void reduce_kernel(const float* __restrict__ scenesR, float* __restrict__ scenes,
                   int K)
{
    int t = blockIdx.x * 256 + threadIdx.x;
    if (t >= SCENE_FLOATS) return;
    int pair = t / PAIR_FLOATS;
    int j    = t - pair * PAIR_FLOATS;
    const float* src = scenesR + (size_t)pair * K * PAIR_FLOATS + j;
    float mx = 0.0f;
    for (int r = 0; r < K; ++r)
        mx = fmaxf(mx, src[(size_t)r * PAIR_FLOATS]);
    scenes[t] = mx;
}

// ---------------------------------------------------------------------------
// conv1: scenes [B,12,15,15,15] -> yA [B,8,8,8,8] (raw conv+bias) + stats[0]
// grid: (b,co,od)=256 blocks; threads 256 = (ciq,oh,ow)
// ---------------------------------------------------------------------------
__global__ __launch_bounds__(256)
void conv1_kernel(const float* __restrict__ scenes,
                  const float* __restrict__ w,    // [8,12,125]
                  const float* __restrict__ bias, // [8]
                  float* __restrict__ y, float* __restrict__ stats)
{
    __shared__ float sred[256];
    int bx = blockIdx.x;
    int od = bx & 7, co = (bx >> 3) & 7, b = bx >> 6;
    int tid = threadIdx.x;
    int ow = tid & 7, oh = (tid >> 3) & 7, ciq = tid >> 6;

    float s = 0.0f;
    for (int cin = 0; cin < 3; ++cin) {
        int ci = ciq * 3 + cin;
        const float* sc = scenes + (size_t)(b * 12 + ci) * G3;
        const float* wc = w + (size_t)(co * 12 + ci) * 125;
#pragma unroll
        for (int kd = 0; kd < 5; ++kd) {
            int id = od * 2 - 2 + kd;
            if ((unsigned)id >= (unsigned)G) continue;   // block-uniform
#pragma unroll
            for (int kh = 0; kh < 5; ++kh) {
                int ih = oh * 2 - 2 + kh;
                bool hok = (unsigned)ih < (unsigned)G;
#pragma unroll
                for (int kw = 0; kw < 5; ++kw) {
                    int iw = ow * 2 - 2 + kw;
                    if (hok && (unsigned)iw < (unsigned)G)
                        s = fmaf(sc[(id * G + ih) * G + iw], wc[kd*25 + kh*5 + kw], s);
                }
            }
        }
    }
    sred[tid] = s;
    __syncthreads();
    if (tid < 64) {
        float tot = sred[tid] + sred[64+tid] + sred[128+tid] + sred[192+tid] + bias[co];
        y[(size_t)(b * 8 + co) * 512 + od * 64 + tid] = tot;
        float sum = tot, sq = tot * tot;
#pragma unroll
        for (int o = 32; o > 0; o >>= 1) {
            sum += __shfl_down(sum, o, 64);
            sq  += __shfl_down(sq,  o, 64);
        }
        if (tid == 0) { atomicAdd(&stats[co], sum); atomicAdd(&stats[8 + co], sq); }
    }
}

// ---------------------------------------------------------------------------
// tail32: 6x(BN+ELU+conv) + final BN+ELU in ONE plain kernel, 32 blocks.
// Block (b,co) computes y[b,co,:] each layer. Cross-block exchange:
//   - y via __hip_atomic_store/load (AGENT scope) -> XCD-coherent, no fences
//   - stats via device atomicAdd
//   - 32-block counter barrier (release add + acquire spin, s_sleep backoff)
// Per barrier ~1-2us vs ~40us for cg::grid.sync (round-3 measurement) and
// ~15-20us per kernel-launch step (round-2 chain).
// ---------------------------------------------------------------------------
__global__ __launch_bounds__(256)
void tail32_kernel(const float* __restrict__ yA, float* __restrict__ yB,
                   float* __restrict__ yC,
                   const float* __restrict__ csw,  // [6,8,8,125]
                   const float* __restrict__ csb,  // [6,8]
                   const float* __restrict__ bn1_g, const float* __restrict__ bn1_b,
                   const float* __restrict__ bns_g, const float* __restrict__ bns_b,
                   float* __restrict__ stats, unsigned* __restrict__ bar,
                   float* __restrict__ outp)
{
    __shared__ float slab[8 * 12 * 144];   // [ci][id+2][ih+2][iw+2] padded, 55.3KB
    __shared__ float sred[256];
    __shared__ float sfinal[512];          // this block's last-layer raw output
    __shared__ float sstat[16], sscale[8], sshift[8];

    int tid = threadIdx.x;
    int bx  = blockIdx.x;
    int co = bx & 7, b = bx >> 3;

    const float* yin = yA;
    float* yout = yB;
    unsigned gen = 0;

    for (int layer = 0; layer < 6; ++layer) {
        const float* g   = (layer == 0) ? bn1_g : (bns_g + (layer - 1) * 8);
        const float* bet = (layer == 0) ? bn1_b : (bns_b + (layer - 1) * 8);
        const float* stats_in  = stats + layer * 16;
        float*       stats_out = stats + (layer + 1) * 16;
        const float* w = csw + (size_t)layer * 8000;

        // stats of the input (written by conv1 / previous layer) -> LDS
        if (tid < 16)
            sstat[tid] = __hip_atomic_load(stats_in + tid, __ATOMIC_RELAXED,
                                           __HIP_MEMORY_SCOPE_AGENT);
        // zero padded slab
        for (int i = tid; i < 8 * 12 * 144; i += 256) slab[i] = 0.0f;
        __syncthreads();
        if (tid < 8) {
            float S = sstat[tid], Q = sstat[8 + tid];
            float m  = S * (1.0f / 2048.0f);
            float vv = Q * (1.0f / 2048.0f) - m * m;
            float rs = rsqrtf(vv + 1e-5f);
            float sc = g[tid] * rs;
            sscale[tid] = sc;
            sshift[tid] = bet[tid] - m * sc;
        }
        __syncthreads();

        // stage BN+ELU'd full y[b] into padded slab (coherent loads)
        for (int s = tid; s < 4096; s += 256) {
            int ci = s >> 9, r = s & 511;
            int id = r >> 6, ih = (r >> 3) & 7, iw = r & 7;
            const float* src = yin + ((size_t)(b * 8 + ci) << 9) + r;
            float raw = (layer == 0)
                ? *src   // yA written by conv1 in a previous kernel: coherent
                : __hip_atomic_load(src, __ATOMIC_RELAXED, __HIP_MEMORY_SCOPE_AGENT);
            float t = fmaf(raw, sscale[ci], sshift[ci]);
            slab[ci * 1728 + (id + 2) * 144 + (ih + 2) * 12 + (iw + 2)] =
                t > 0.0f ? t : __expf(t) - 1.0f;
        }
        __syncthreads();

        // conv: loop over od; thread = (ow, oh, ciq); ciq covers 2 ci
        int ow = tid & 7, oh = (tid >> 3) & 7, ciq = tid >> 6;
        float sum_acc = 0.0f, sq_acc = 0.0f;
        for (int od = 0; od < 8; ++od) {
            float s = 0.0f;
#pragma unroll
            for (int c2 = 0; c2 < 2; ++c2) {
                int ci = ciq * 2 + c2;
                const float* sl = slab + ci * 1728 + od * 144;   // id = od+kd
                const float* wc = w + (size_t)(co * 8 + ci) * 125;
#pragma unroll
                for (int kd = 0; kd < 5; ++kd) {
#pragma unroll
                    for (int kh = 0; kh < 5; ++kh) {
                        const float* row = sl + kd * 144 + (oh + kh) * 12 + ow;
                        const float* wr = wc + kd * 25 + kh * 5;
#pragma unroll
                        for (int kw = 0; kw < 5; ++kw) s = fmaf(row[kw], wr[kw], s);
                    }
                }
            }
            sred[tid] = s;
            __syncthreads();
            if (tid < 64) {
                float tot = sred[tid] + sred[64+tid] + sred[128+tid] + sred[192+tid]
                          + csb[layer * 8 + co];
                sfinal[od * 64 + tid] = tot;
                sum_acc += tot;
                sq_acc  += tot * tot;
                if (layer < 5)   // last layer's y is only needed by this block
                    __hip_atomic_store(yout + ((size_t)(b * 8 + co) << 9) + od * 64 + tid,
                                       tot, __ATOMIC_RELAXED, __HIP_MEMORY_SCOPE_AGENT);
            }
            __syncthreads();
        }
        if (tid < 64) {
#pragma unroll
            for (int o = 32; o > 0; o >>= 1) {
                sum_acc += __shfl_down(sum_acc, o, 64);
                sq_acc  += __shfl_down(sq_acc,  o, 64);
            }
            if (tid == 0) {
                atomicAdd(stats_out + co, sum_acc);
                atomicAdd(stats_out + 8 + co, sq_acc);
            }
        }

        // 32-block barrier: release-add, acquire-spin with sleep backoff
        ++gen;
        __syncthreads();
        if (tid == 0) {
            __hip_atomic_fetch_add(bar, 1u, __ATOMIC_ACQ_REL, __HIP_MEMORY_SCOPE_AGENT);
            while (__hip_atomic_load(bar, __ATOMIC_ACQUIRE, __HIP_MEMORY_SCOPE_AGENT)
                   < 32u * gen)
                __builtin_amdgcn_s_sleep(2);
        }
        __syncthreads();

        // ping-pong: L0: A->B; L1: B->C; L2: C->B; ...
        if (layer == 0) { yin = yB; yout = yC; }
        else { float* t_ = yout; yout = (float*)yin; yin = t_; }
    }

    // final BN+ELU from this block's own last-layer output (sfinal) + stats[6]
    if (tid < 16)
        sstat[tid] = __hip_atomic_load(stats + 6 * 16 + tid, __ATOMIC_RELAXED,
                                       __HIP_MEMORY_SCOPE_AGENT);
    __syncthreads();
    if (tid < 64) {
        float S = sstat[co], Q = sstat[8 + co];
        float m  = S * (1.0f / 2048.0f);
        float vv = Q * (1.0f / 2048.0f) - m * m;
        float rs = rsqrtf(vv + 1e-5f);
        float sc = (bns_g + 5 * 8)[co] * rs;
        float sh = (bns_b + 5 * 8)[co] - m * sc;
#pragma unroll
        for (int od = 0; od < 8; ++od) {
            float t = fmaf(sfinal[od * 64 + tid], sc, sh);
            outp[((size_t)(b * 8 + co) << 9) + od * 64 + tid] =
                t > 0.0f ? t : __expf(t) - 1.0f;
        }
    }
}

// ---------------------------------------------------------------------------
extern "C" void kernel_launch(void* const* d_in, const int* in_sizes, int n_in,
                              void* d_out, int out_size, void* d_ws, size_t ws_size,
                              hipStream_t stream)
{
    const float* goals       = (const float*)d_in[0];
    const float* inputs      = (const float*)d_in[1];
    const float* backgrounds = (const float*)d_in[2];
    const float* W1 = (const float*)d_in[3];
    const float* b1 = (const float*)d_in[4];
    const float* W2 = (const float*)d_in[5];
    const float* b2 = (const float*)d_in[6];
    const float* W3 = (const float*)d_in[7];
    const float* b3 = (const float*)d_in[8];
    const float* conv1_w = (const float*)d_in[9];
    const float* conv1_b = (const float*)d_in[10];
    const float* bn1_g   = (const float*)d_in[11];
    const float* bn1_b   = (const float*)d_in[12];
    const float* convs_w = (const float*)d_in[13];
    const float* convs_b = (const float*)d_in[14];
    const float* bns_g   = (const float*)d_in[15];
    const float* bns_b   = (const float*)d_in[16];

    // --- pick (K replicas, S segments) to fit the workspace -----------------
    long ws_floats = (long)(ws_size / 4);
    long fixed = SCENE_FLOATS + 3L * 16384 + 128;
    static const int plans[][2] = {
        {42,1},{42,2},{42,4},{24,4},{21,6},{16,8},{8,12},{4,16},{2,32},{1,64}};
    int K = 1, S = 64;
    for (int pi = 0; pi < 10; ++pi) {
        int pk = plans[pi][0], ps = plans[pi][1];
        long mseg = (NPTS + ps - 1) / ps;
        long need = 60L * mseg + (long)pk * SCENE_FLOATS + fixed;
        if (need <= ws_floats) { K = pk; S = ps; break; }
    }
    int Mseg = (NPTS + S - 1) / S;

    float*    wsp     = (float*)d_ws;
    float4*   vals    = (float4*)wsp;                          // 12*Mseg float4
    int*      cells   = (int*)(wsp + 48L * Mseg);              // 12*Mseg ints
    float*    scenesR = wsp + 60L * Mseg;                      // K * SCENE_FLOATS
    float*    scenes  = scenesR + (size_t)K * SCENE_FLOATS;    // 162000
    float*    yA      = scenes + SCENE_FLOATS;                 // 16384
    float*    yB      = yA + 16384;                            // 16384
    float*    yC      = yB + 16384;                            // 16384
    float*    stats   = yC + 16384;                            // 7*16 floats
    unsigned* bar     = (unsigned*)(stats + 112);              // barrier counter

    // zero stats (112 floats) + barrier counter (covered by 128-float region)
    hipMemsetAsync(stats, 0, 128 * sizeof(float), stream);

    for (int s = 0; s < S; ++s) {
        int s0 = s * Mseg;
        int m  = min(Mseg, NPTS - s0);
        dim3 agrid((m + 255) / 256, B, 3);
        mlp_kernel<<<agrid, 256, 0, stream>>>(inputs, goals, backgrounds,
                                              W1, b1, W2, b2, W3, b3,
                                              vals, cells, s0, m);
        dim3 bgrid(K, B, 3);
        scatter_kernel<<<bgrid, 512, 0, stream>>>(vals, cells, scenesR, K, m,
                                                  s > 0 ? 1 : 0);
    }

    reduce_kernel<<<(SCENE_FLOATS + 255) / 256, 256, 0, stream>>>(scenesR, scenes, K);

    conv1_kernel<<<256, 256, 0, stream>>>(scenes, conv1_w, conv1_b, yA, stats);

    tail32_kernel<<<32, 256, 0, stream>>>(yA, yB, yC, convs_w, convs_b,
                                          bn1_g, bn1_b, bns_g, bns_b,
                                          stats, bar, (float*)d_out);
}

// Round 5
// 469.759 us; speedup vs baseline: 1.1533x; 1.0158x over previous
//
#include <hip/hip_runtime.h>
#include <math.h>

#define B 4
#define NPTS 300000
#define G 15
#define G3 3375
#define PAIR_FLOATS (4*G3)       // 13500 floats: one (b,set) grid, 4 channels
#define SCENE_FLOATS (B*12*G3)   // 162000

__device__ __forceinline__ float eluf(float v) {
    return v > 0.0f ? v : __expf(v) - 1.0f;
}

// memory-side RMW-as-load / RMW-as-store: coherent across XCDs with NO
// acquire/release fences (fences trigger the ~42us L2 wb/inv per layer
// measured in rounds 3+4).
__device__ __forceinline__ float coh_load(const float* p) {
    return __hip_atomic_fetch_add((float*)p, 0.0f, __ATOMIC_RELAXED,
                                  __HIP_MEMORY_SCOPE_AGENT);
}
__device__ __forceinline__ void coh_store(float* p, float v) {
    __hip_atomic_exchange(p, v, __ATOMIC_RELAXED, __HIP_MEMORY_SCOPE_AGENT);
}

// ---------------------------------------------------------------------------
// Phase A: pure MLP. One point per thread, NO loop, NO atomics, NO LDS.
// Weights consumed straight from the scalar cache (24 VGPR codegen).
// ---------------------------------------------------------------------------
__global__ __launch_bounds__(256)
void mlp_kernel(const float* __restrict__ P0,   // inputs  (set 0)
                const float* __restrict__ P1,   // goals   (set 1)
                const float* __restrict__ P2,   // backgrounds (set 2)
                const float* __restrict__ W1, const float* __restrict__ b1,
                const float* __restrict__ W2, const float* __restrict__ b2,
                const float* __restrict__ W3, const float* __restrict__ b3,
                float4* __restrict__ vals, int* __restrict__ cells,
                int s0, int m)
{
    int b   = blockIdx.y;
    int set = blockIdx.z;
    int i   = blockIdx.x * 256 + threadIdx.x;
    if (i >= m) return;
    const float* P = (set == 0) ? P0 : ((set == 1) ? P1 : P2);

    const float* p = P + ((size_t)b * NPTS + (size_t)(s0 + i)) * 3;
    float px = p[0], py = p[1], pz = p[2];

    const float HI = 14.9999f;  // GZ - 1e-4
    float cx = floorf(fminf(fmaxf(px, 0.0f), HI));
    float cy = floorf(fminf(fmaxf(py, 0.0f), HI));
    float cz = floorf(fminf(fmaxf(pz, 0.0f), HI));

    float x[12];
    x[0] = px - (cx + 0.5f); x[1] = py - (cy + 0.5f); x[2] = pz - (cz + 0.5f);
    x[3] = px - cx;          x[4] = py - cy;          x[5] = pz - cz;
    x[6] = px - (cx + 1.0f); x[7] = py - (cy + 1.0f); x[8] = pz - (cz + 1.0f);
    x[9]  = sqrtf(x[0]*x[0] + x[1]*x[1] + x[2]*x[2]);
    x[10] = sqrtf(x[3]*x[3] + x[4]*x[4] + x[5]*x[5]);
    x[11] = sqrtf(x[6]*x[6] + x[7]*x[7] + x[8]*x[8]);

    float h1[16];
#pragma unroll
    for (int j = 0; j < 16; ++j) {
        float s = b1[j];
#pragma unroll
        for (int k = 0; k < 12; ++k) s = fmaf(x[k], W1[k*16 + j], s);
        h1[j] = eluf(s);
    }
    float h2[16];
#pragma unroll
    for (int j = 0; j < 16; ++j) {
        float s = b2[j];
#pragma unroll
        for (int k = 0; k < 16; ++k) s = fmaf(h1[k], W2[k*16 + j], s);
        h2[j] = eluf(s);
    }
    float o[4];
#pragma unroll
    for (int j = 0; j < 4; ++j) {
        float s = b3[j];
#pragma unroll
        for (int k = 0; k < 16; ++k) s = fmaf(h2[k], W3[k*4 + j], s);
        o[j] = s;
    }

    int cell = (((int)cx) * G + (int)cy) * G + (int)cz;
    int pair = b * 3 + set;
    vals [(size_t)pair * m + i] = make_float4(o[0], o[1], o[2], o[3]);
    cells[(size_t)pair * m + i] = cell;
}

// ---------------------------------------------------------------------------
// Phase B: scatter-max into a PRIVATE LDS grid (54 KB), flush with plain
// stores into this block's replica. 512 threads for latency hiding.
// grid: (K, B, 3); block 512.
// ---------------------------------------------------------------------------
__global__ __launch_bounds__(512)
void scatter_kernel(const float4* __restrict__ vals,
                    const int* __restrict__ cells,
                    float* __restrict__ scenesR, int K, int m, int carry)
{
    __shared__ unsigned sg[PAIR_FLOATS];   // uint-ordered positive floats

    int rep = blockIdx.x;
    int b   = blockIdx.y;
    int set = blockIdx.z;
    int pair = b * 3 + set;
    float* myrep = scenesR + ((size_t)pair * K + rep) * PAIR_FLOATS;

    if (carry) {
        for (int i = threadIdx.x; i < PAIR_FLOATS; i += 512)
            sg[i] = __float_as_uint(myrep[i]);     // values are >= 0
    } else {
        for (int i = threadIdx.x; i < PAIR_FLOATS; i += 512)
            sg[i] = 0u;
    }
    __syncthreads();

    int chunk = (m + K - 1) / K;
    int start = rep * chunk;
    int end   = min(m, start + chunk);
    const float4* v = vals  + (size_t)pair * m;
    const int*    c = cells + (size_t)pair * m;

    for (int i = start + (int)threadIdx.x; i < end; i += 512) {
        float4 o = v[i];
        int cell = c[i];
        if (o.x > 0.0f) atomicMax(&sg[          cell], __float_as_uint(o.x));
        if (o.y > 0.0f) atomicMax(&sg[    G3 + cell], __float_as_uint(o.y));
        if (o.z > 0.0f) atomicMax(&sg[2 * G3 + cell], __float_as_uint(o.z));
        if (o.w > 0.0f) atomicMax(&sg[3 * G3 + cell], __float_as_uint(o.w));
    }
    __syncthreads();

    for (int i = threadIdx.x; i < PAIR_FLOATS; i += 512)
        myrep[i] = __uint_as_float(sg[i]);
}

// ---------------------------------------------------------------------------
// max-reduce K replicas per pair -> scenes [B,12,G3]
// ---------------------------------------------------------------------------
__global__ __launch_bounds__(256)
void reduce_kernel(const float* __restrict__ scenesR, float* __restrict__ scenes,
                   int K)
{
    int t = blockIdx.x * 256 + threadIdx.x;
    if (t >= SCENE_FLOATS) return;
    int pair = t / PAIR_FLOATS;
    int j    = t - pair * PAIR_FLOATS;
    const float* src = scenesR + (size_t)pair * K * PAIR_FLOATS + j;
    float mx = 0.0f;
    for (int r = 0; r < K; ++r)
        mx = fmaxf(mx, src[(size_t)r * PAIR_FLOATS]);
    scenes[t] = mx;
}

// ---------------------------------------------------------------------------
// conv1: scenes [B,12,15,15,15] -> yA [B,8,8,8,8] (raw conv+bias) + stats[0]
// grid: (b,co,od)=256 blocks; threads 256 = (ciq,oh,ow)
// ---------------------------------------------------------------------------
__global__ __launch_bounds__(256)
void conv1_kernel(const float* __restrict__ scenes,
                  const float* __restrict__ w,    // [8,12,125]
                  const float* __restrict__ bias, // [8]
                  float* __restrict__ y, float* __restrict__ stats)
{
    __shared__ float sred[256];
    int bx = blockIdx.x;
    int od = bx & 7, co = (bx >> 3) & 7, b = bx >> 6;
    int tid = threadIdx.x;
    int ow = tid & 7, oh = (tid >> 3) & 7, ciq = tid >> 6;

    float s = 0.0f;
    for (int cin = 0; cin < 3; ++cin) {
        int ci = ciq * 3 + cin;
        const float* sc = scenes + (size_t)(b * 12 + ci) * G3;
        const float* wc = w + (size_t)(co * 12 + ci) * 125;
#pragma unroll
        for (int kd = 0; kd < 5; ++kd) {
            int id = od * 2 - 2 + kd;
            if ((unsigned)id >= (unsigned)G) continue;   // block-uniform
#pragma unroll
            for (int kh = 0; kh < 5; ++kh) {
                int ih = oh * 2 - 2 + kh;
                bool hok = (unsigned)ih < (unsigned)G;
#pragma unroll
                for (int kw = 0; kw < 5; ++kw) {
                    int iw = ow * 2 - 2 + kw;
                    if (hok && (unsigned)iw < (unsigned)G)
                        s = fmaf(sc[(id * G + ih) * G + iw], wc[kd*25 + kh*5 + kw], s);
                }
            }
        }
    }
    sred[tid] = s;
    __syncthreads();
    if (tid < 64) {
        float tot = sred[tid] + sred[64+tid] + sred[128+tid] + sred[192+tid] + bias[co];
        y[(size_t)(b * 8 + co) * 512 + od * 64 + tid] = tot;
        float sum = tot, sq = tot * tot;
#pragma unroll
        for (int o = 32; o > 0; o >>= 1) {
            sum += __shfl_down(sum, o, 64);
            sq  += __shfl_down(sq,  o, 64);
        }
        if (tid == 0) { atomicAdd(&stats[co], sum); atomicAdd(&stats[8 + co], sq); }
    }
}

// ---------------------------------------------------------------------------
// tail32: 6x(BN+ELU+conv) + final BN+ELU in ONE plain kernel, 32 blocks.
// ALL cross-block traffic is relaxed memory-side atomic RMW (coherent across
// XCDs with no fences). No acquire/release anywhere -> no L2 wb/inv -> the
// read-only weights stay cached across all layers. Barrier ordering comes
// from __syncthreads() (drains each wave's vmcnt before s_barrier), so all
// of a block's atomicExch's are ACK'd at the coherence point before tid0
// publishes its arrival.
// ---------------------------------------------------------------------------
__global__ __launch_bounds__(256)
void tail32_kernel(const float* __restrict__ yA, float* __restrict__ yB,
                   float* __restrict__ yC,
                   const float* __restrict__ csw,  // [6,8,8,125]
                   const float* __restrict__ csb,  // [6,8]
                   const float* __restrict__ bn1_g, const float* __restrict__ bn1_b,
                   const float* __restrict__ bns_g, const float* __restrict__ bns_b,
                   float* __restrict__ stats, unsigned* __restrict__ bar,
                   float* __restrict__ outp)
{
    __shared__ float slab[8 * 12 * 144];   // [ci][id+2][ih+2][iw pad12], 55.3KB
    __shared__ float sred[256];
    __shared__ float sfinal[512];          // this block's last-layer raw output
    __shared__ float sstat[16], sscale[8], sshift[8];

    int tid = threadIdx.x;
    int bx  = blockIdx.x;
    int co = bx & 7, b = bx >> 3;

    // zero slab ONCE: staging only ever writes the interior, padding stays 0
    for (int i = tid; i < 8 * 12 * 144; i += 256) slab[i] = 0.0f;

    const float* yin = yA;
    float* yout = yB;
    unsigned gen = 0;

    for (int layer = 0; layer < 6; ++layer) {
        const float* g   = (layer == 0) ? bn1_g : (bns_g + (layer - 1) * 8);
        const float* bet = (layer == 0) ? bn1_b : (bns_b + (layer - 1) * 8);
        const float* stats_in  = stats + layer * 16;
        float*       stats_out = stats + (layer + 1) * 16;
        const float* w = csw + (size_t)layer * 8000;

        // input stats -> LDS (RMW-as-load for layers written by other blocks)
        if (tid < 16)
            sstat[tid] = (layer == 0) ? stats_in[tid] : coh_load(stats_in + tid);
        __syncthreads();
        if (tid < 8) {
            float S = sstat[tid], Q = sstat[8 + tid];
            float m  = S * (1.0f / 2048.0f);
            float vv = Q * (1.0f / 2048.0f) - m * m;
            float rs = rsqrtf(vv + 1e-5f);
            float sc = g[tid] * rs;
            sscale[tid] = sc;
            sshift[tid] = bet[tid] - m * sc;
        }
        __syncthreads();

        // stage BN+ELU'd full y[b] into padded slab
        for (int s = tid; s < 4096; s += 256) {
            int ci = s >> 9, r = s & 511;
            int id = r >> 6, ih = (r >> 3) & 7, iw = r & 7;
            const float* src = yin + ((size_t)(b * 8 + ci) << 9) + r;
            float raw = (layer == 0) ? *src : coh_load(src);
            float t = fmaf(raw, sscale[ci], sshift[ci]);
            slab[ci * 1728 + (id + 2) * 144 + (ih + 2) * 12 + (iw + 2)] =
                t > 0.0f ? t : __expf(t) - 1.0f;
        }
        __syncthreads();

        // conv: loop over od; thread = (ow, oh, ciq); ciq covers 2 ci
        int ow = tid & 7, oh = (tid >> 3) & 7, ciq = tid >> 6;
        float sum_acc = 0.0f, sq_acc = 0.0f;
        for (int od = 0; od < 8; ++od) {
            float s = 0.0f;
#pragma unroll
            for (int c2 = 0; c2 < 2; ++c2) {
                int ci = ciq * 2 + c2;
                const float* sl = slab + ci * 1728 + od * 144;   // id = od+kd
                const float* wc = w + (size_t)(co * 8 + ci) * 125;
#pragma unroll
                for (int kd = 0; kd < 5; ++kd) {
#pragma unroll
                    for (int kh = 0; kh < 5; ++kh) {
                        const float* row = sl + kd * 144 + (oh + kh) * 12 + ow;
                        const float* wr = wc + kd * 25 + kh * 5;
#pragma unroll
                        for (int kw = 0; kw < 5; ++kw) s = fmaf(row[kw], wr[kw], s);
                    }
                }
            }
            sred[tid] = s;
            __syncthreads();
            if (tid < 64) {
                float tot = sred[tid] + sred[64+tid] + sred[128+tid] + sred[192+tid]
                          + csb[layer * 8 + co];
                sfinal[od * 64 + tid] = tot;
                sum_acc += tot;
                sq_acc  += tot * tot;
                if (layer < 5)   // last layer's y is only needed by this block
                    coh_store(yout + ((size_t)(b * 8 + co) << 9) + od * 64 + tid, tot);
            }
            __syncthreads();
        }
        if (tid < 64) {
#pragma unroll
            for (int o = 32; o > 0; o >>= 1) {
                sum_acc += __shfl_down(sum_acc, o, 64);
                sq_acc  += __shfl_down(sq_acc,  o, 64);
            }
            if (tid == 0) {
                atomicAdd(stats_out + co, sum_acc);
                atomicAdd(stats_out + 8 + co, sq_acc);
            }
        }

        // 32-block barrier: relaxed arrive + relaxed RMW spin. __syncthreads
        // drains every wave's outstanding atomics before tid0 arrives.
        ++gen;
        __syncthreads();
        if (tid == 0) {
            __hip_atomic_fetch_add(bar, 1u, __ATOMIC_RELAXED,
                                   __HIP_MEMORY_SCOPE_AGENT);
            while (__hip_atomic_fetch_add(bar, 0u, __ATOMIC_RELAXED,
                                          __HIP_MEMORY_SCOPE_AGENT) < 32u * gen)
                __builtin_amdgcn_s_sleep(1);
        }
        __syncthreads();

        // ping-pong: L0: A->B; L1: B->C; L2: C->B; ...
        if (layer == 0) { yin = yB; yout = yC; }
        else { float* t_ = yout; yout = (float*)yin; yin = t_; }
    }

    // final BN+ELU from this block's own last-layer output (sfinal) + stats[6]
    if (tid < 16)
        sstat[tid] = coh_load(stats + 6 * 16 + tid);
    __syncthreads();
    if (tid < 64) {
        float S = sstat[co], Q = sstat[8 + co];
        float m  = S * (1.0f / 2048.0f);
        float vv = Q * (1.0f / 2048.0f) - m * m;
        float rs = rsqrtf(vv + 1e-5f);
        float sc = (bns_g + 5 * 8)[co] * rs;
        float sh = (bns_b + 5 * 8)[co] - m * sc;
#pragma unroll
        for (int od = 0; od < 8; ++od) {
            float t = fmaf(sfinal[od * 64 + tid], sc, sh);
            outp[((size_t)(b * 8 + co) << 9) + od * 64 + tid] =
                t > 0.0f ? t : __expf(t) - 1.0f;
        }
    }
}

// ---------------------------------------------------------------------------
extern "C" void kernel_launch(void* const* d_in, const int* in_sizes, int n_in,
                              void* d_out, int out_size, void* d_ws, size_t ws_size,
                              hipStream_t stream)
{
    const float* goals       = (const float*)d_in[0];
    const float* inputs      = (const float*)d_in[1];
    const float* backgrounds = (const float*)d_in[2];
    const float* W1 = (const float*)d_in[3];
    const float* b1 = (const float*)d_in[4];
    const float* W2 = (const float*)d_in[5];
    const float* b2 = (const float*)d_in[6];
    const float* W3 = (const float*)d_in[7];
    const float* b3 = (const float*)d_in[8];
    const float* conv1_w = (const float*)d_in[9];
    const float* conv1_b = (const float*)d_in[10];
    const float* bn1_g   = (const float*)d_in[11];
    const float* bn1_b   = (const float*)d_in[12];
    const float* convs_w = (const float*)d_in[13];
    const float* convs_b = (const float*)d_in[14];
    const float* bns_g   = (const float*)d_in[15];
    const float* bns_b   = (const float*)d_in[16];

    // --- pick (K replicas, S segments) to fit the workspace -----------------
    long ws_floats = (long)(ws_size / 4);
    long fixed = SCENE_FLOATS + 3L * 16384 + 128;
    static const int plans[][2] = {
        {42,1},{42,2},{42,4},{24,4},{21,6},{16,8},{8,12},{4,16},{2,32},{1,64}};
    int K = 1, S = 64;
    for (int pi = 0; pi < 10; ++pi) {
        int pk = plans[pi][0], ps = plans[pi][1];
        long mseg = (NPTS + ps - 1) / ps;
        long need = 60L * mseg + (long)pk * SCENE_FLOATS + fixed;
        if (need <= ws_floats) { K = pk; S = ps; break; }
    }
    int Mseg = (NPTS + S - 1) / S;

    float*    wsp     = (float*)d_ws;
    float4*   vals    = (float4*)wsp;                          // 12*Mseg float4
    int*      cells   = (int*)(wsp + 48L * Mseg);              // 12*Mseg ints
    float*    scenesR = wsp + 60L * Mseg;                      // K * SCENE_FLOATS
    float*    scenes  = scenesR + (size_t)K * SCENE_FLOATS;    // 162000
    float*    yA      = scenes + SCENE_FLOATS;                 // 16384
    float*    yB      = yA + 16384;                            // 16384
    float*    yC      = yB + 16384;                            // 16384
    float*    stats   = yC + 16384;                            // 7*16 floats
    unsigned* bar     = (unsigned*)(stats + 112);              // barrier counter

    // zero stats (112 floats) + barrier counter (covered by 128-float region)
    hipMemsetAsync(stats, 0, 128 * sizeof(float), stream);

    for (int s = 0; s < S; ++s) {
        int s0 = s * Mseg;
        int m  = min(Mseg, NPTS - s0);
        dim3 agrid((m + 255) / 256, B, 3);
        mlp_kernel<<<agrid, 256, 0, stream>>>(inputs, goals, backgrounds,
                                              W1, b1, W2, b2, W3, b3,
                                              vals, cells, s0, m);
        dim3 bgrid(K, B, 3);
        scatter_kernel<<<bgrid, 512, 0, stream>>>(vals, cells, scenesR, K, m,
                                                  s > 0 ? 1 : 0);
    }

    reduce_kernel<<<(SCENE_FLOATS + 255) / 256, 256, 0, stream>>>(scenesR, scenes, K);

    conv1_kernel<<<256, 256, 0, stream>>>(scenes, conv1_w, conv1_b, yA, stats);

    tail32_kernel<<<32, 256, 0, stream>>>(yA, yB, yC, convs_w, convs_b,
                                          bn1_g, bn1_b, bns_g, bns_b,
                                          stats, bar, (float*)d_out);
}

// Round 6
// 301.732 us; speedup vs baseline: 1.7955x; 1.5569x over previous
//
#include <hip/hip_runtime.h>
#include <math.h>

#define B 4
#define NPTS 300000
#define G 15
#define G3 3375
#define PAIR_FLOATS (4*G3)       // 13500 floats: one (b,set) grid, 4 channels
#define SCENE_FLOATS (B*12*G3)   // 162000

__device__ __forceinline__ float eluf(float v) {
    return v > 0.0f ? v : __expf(v) - 1.0f;
}

// ---------------------------------------------------------------------------
// Phase A: pure MLP. One point per thread, NO loop, NO atomics, NO LDS.
// Weights consumed straight from the scalar cache (24 VGPR codegen).
// Block (0,0,0) also zeroes the stats buffer (saves a memset dispatch;
// stream order guarantees completion before conv1 reads it 3 dispatches on).
// ---------------------------------------------------------------------------
__global__ __launch_bounds__(256)
void mlp_kernel(const float* __restrict__ P0,   // inputs  (set 0)
                const float* __restrict__ P1,   // goals   (set 1)
                const float* __restrict__ P2,   // backgrounds (set 2)
                const float* __restrict__ W1, const float* __restrict__ b1,
                const float* __restrict__ W2, const float* __restrict__ b2,
                const float* __restrict__ W3, const float* __restrict__ b3,
                float4* __restrict__ vals, int* __restrict__ cells,
                float* __restrict__ stats,
                int s0, int m)
{
    if (blockIdx.x == 0 && blockIdx.y == 0 && blockIdx.z == 0 && threadIdx.x < 128)
        stats[threadIdx.x] = 0.0f;

    int b   = blockIdx.y;
    int set = blockIdx.z;
    int i   = blockIdx.x * 256 + threadIdx.x;
    if (i >= m) return;
    const float* P = (set == 0) ? P0 : ((set == 1) ? P1 : P2);

    const float* p = P + ((size_t)b * NPTS + (size_t)(s0 + i)) * 3;
    float px = p[0], py = p[1], pz = p[2];

    const float HI = 14.9999f;  // GZ - 1e-4
    float cx = floorf(fminf(fmaxf(px, 0.0f), HI));
    float cy = floorf(fminf(fmaxf(py, 0.0f), HI));
    float cz = floorf(fminf(fmaxf(pz, 0.0f), HI));

    float x[12];
    x[0] = px - (cx + 0.5f); x[1] = py - (cy + 0.5f); x[2] = pz - (cz + 0.5f);
    x[3] = px - cx;          x[4] = py - cy;          x[5] = pz - cz;
    x[6] = px - (cx + 1.0f); x[7] = py - (cy + 1.0f); x[8] = pz - (cz + 1.0f);
    x[9]  = sqrtf(x[0]*x[0] + x[1]*x[1] + x[2]*x[2]);
    x[10] = sqrtf(x[3]*x[3] + x[4]*x[4] + x[5]*x[5]);
    x[11] = sqrtf(x[6]*x[6] + x[7]*x[7] + x[8]*x[8]);

    float h1[16];
#pragma unroll
    for (int j = 0; j < 16; ++j) {
        float s = b1[j];
#pragma unroll
        for (int k = 0; k < 12; ++k) s = fmaf(x[k], W1[k*16 + j], s);
        h1[j] = eluf(s);
    }
    float h2[16];
#pragma unroll
    for (int j = 0; j < 16; ++j) {
        float s = b2[j];
#pragma unroll
        for (int k = 0; k < 16; ++k) s = fmaf(h1[k], W2[k*16 + j], s);
        h2[j] = eluf(s);
    }
    float o[4];
#pragma unroll
    for (int j = 0; j < 4; ++j) {
        float s = b3[j];
#pragma unroll
        for (int k = 0; k < 16; ++k) s = fmaf(h2[k], W3[k*4 + j], s);
        o[j] = s;
    }

    int cell = (((int)cx) * G + (int)cy) * G + (int)cz;
    int pair = b * 3 + set;
    vals [(size_t)pair * m + i] = make_float4(o[0], o[1], o[2], o[3]);
    cells[(size_t)pair * m + i] = cell;
}

// ---------------------------------------------------------------------------
// Phase B: scatter-max into a PRIVATE LDS grid (54 KB), flush with plain
// stores into this block's replica. 512 threads for latency hiding.
// grid: (K, B, 3); block 512.
// ---------------------------------------------------------------------------
__global__ __launch_bounds__(512)
void scatter_kernel(const float4* __restrict__ vals,
                    const int* __restrict__ cells,
                    float* __restrict__ scenesR, int K, int m, int carry)
{
    __shared__ unsigned sg[PAIR_FLOATS];   // uint-ordered positive floats

    int rep = blockIdx.x;
    int b   = blockIdx.y;
    int set = blockIdx.z;
    int pair = b * 3 + set;
    float* myrep = scenesR + ((size_t)pair * K + rep) * PAIR_FLOATS;

    if (carry) {
        for (int i = threadIdx.x; i < PAIR_FLOATS; i += 512)
            sg[i] = __float_as_uint(myrep[i]);     // values are >= 0
    } else {
        for (int i = threadIdx.x; i < PAIR_FLOATS; i += 512)
            sg[i] = 0u;
    }
    __syncthreads();

    int chunk = (m + K - 1) / K;
    int start = rep * chunk;
    int end   = min(m, start + chunk);
    const float4* v = vals  + (size_t)pair * m;
    const int*    c = cells + (size_t)pair * m;

    for (int i = start + (int)threadIdx.x; i < end; i += 512) {
        float4 o = v[i];
        int cell = c[i];
        if (o.x > 0.0f) atomicMax(&sg[          cell], __float_as_uint(o.x));
        if (o.y > 0.0f) atomicMax(&sg[    G3 + cell], __float_as_uint(o.y));
        if (o.z > 0.0f) atomicMax(&sg[2 * G3 + cell], __float_as_uint(o.z));
        if (o.w > 0.0f) atomicMax(&sg[3 * G3 + cell], __float_as_uint(o.w));
    }
    __syncthreads();

    for (int i = threadIdx.x; i < PAIR_FLOATS; i += 512)
        myrep[i] = __uint_as_float(sg[i]);
}

// ---------------------------------------------------------------------------
// max-reduce K replicas per pair -> scenes [B,12,G3]
// ---------------------------------------------------------------------------
__global__ __launch_bounds__(256)
void reduce_kernel(const float* __restrict__ scenesR, float* __restrict__ scenes,
                   int K)
{
    int t = blockIdx.x * 256 + threadIdx.x;
    if (t >= SCENE_FLOATS) return;
    int pair = t / PAIR_FLOATS;
    int j    = t - pair * PAIR_FLOATS;
    const float* src = scenesR + (size_t)pair * K * PAIR_FLOATS + j;
    float mx = 0.0f;
    for (int r = 0; r < K; ++r)
        mx = fmaxf(mx, src[(size_t)r * PAIR_FLOATS]);
    scenes[t] = mx;
}

// ---------------------------------------------------------------------------
// conv1: scenes [B,12,15,15,15] -> y0 [B,8,8,8,8] (raw conv+bias) + stats0
// grid: (b,co,od)=256 blocks; threads 256 = (ciq,oh,ow); ciq handles 3 ci
// ---------------------------------------------------------------------------
__global__ __launch_bounds__(256)
void conv1_kernel(const float* __restrict__ scenes,
                  const float* __restrict__ w,    // [8,12,125]
                  const float* __restrict__ bias, // [8]
                  float* __restrict__ y, float* __restrict__ stats)
{
    __shared__ float sred[256];
    int bx = blockIdx.x;
    int od = bx & 7, co = (bx >> 3) & 7, b = bx >> 6;
    int tid = threadIdx.x;
    int ow = tid & 7, oh = (tid >> 3) & 7, ciq = tid >> 6;

    float s = 0.0f;
    for (int cin = 0; cin < 3; ++cin) {
        int ci = ciq * 3 + cin;
        const float* sc = scenes + (size_t)(b * 12 + ci) * G3;
        const float* wc = w + (size_t)(co * 12 + ci) * 125;
#pragma unroll
        for (int kd = 0; kd < 5; ++kd) {
            int id = od * 2 - 2 + kd;
            if ((unsigned)id >= (unsigned)G) continue;   // block-uniform
#pragma unroll
            for (int kh = 0; kh < 5; ++kh) {
                int ih = oh * 2 - 2 + kh;
                bool hok = (unsigned)ih < (unsigned)G;
#pragma unroll
                for (int kw = 0; kw < 5; ++kw) {
                    int iw = ow * 2 - 2 + kw;
                    if (hok && (unsigned)iw < (unsigned)G)
                        s = fmaf(sc[(id * G + ih) * G + iw], wc[kd*25 + kh*5 + kw], s);
                }
            }
        }
    }
    sred[tid] = s;
    __syncthreads();
    if (tid < 64) {
        float tot = sred[tid] + sred[64+tid] + sred[128+tid] + sred[192+tid] + bias[co];
        y[(size_t)(b * 8 + co) * 512 + od * 64 + tid] = tot;
        float sum = tot, sq = tot * tot;
#pragma unroll
        for (int o = 32; o > 0; o >>= 1) {
            sum += __shfl_down(sum, o, 64);
            sq  += __shfl_down(sq,  o, 64);
        }
        if (tid == 0) { atomicAdd(&stats[co], sum); atomicAdd(&stats[8 + co], sq); }
    }
}

// ---------------------------------------------------------------------------
// conv_s: BN(stats_in,g,beta)+ELU applied to yin on the fly, then 5^3 conv.
// v2: issue ALL raw y loads FIRST (16/thread, unguarded), overlap the
// stats->rsqrt->scale chain and slab zeroing under them, then scatter
// BN+ELU'd values into the padded slab. Removes the serial
// [stats-chain -> barrier -> y-load-chain] latency stack of the old version.
// grid: (b,co,od)=256 blocks; 256 threads.
// ---------------------------------------------------------------------------
__global__ __launch_bounds__(256)
void conv_s_kernel(const float* __restrict__ yin,
                   const float* __restrict__ w,     // [8,8,125] this layer
                   const float* __restrict__ bias,  // [8]
                   const float* __restrict__ g, const float* __restrict__ bet,
                   const float* __restrict__ stats_in,
                   float* __restrict__ yout, float* __restrict__ stats_out)
{
    __shared__ float slab[8 * 5 * 144];   // [ci][kd][12][12], zero-padded
    __shared__ float sstat[16], sscale[8], sshift[8];
    __shared__ float sred[256];

    int bx = blockIdx.x;
    int od = bx & 7, co = (bx >> 3) & 7, b = bx >> 6;
    int tid = threadIdx.x;

    // 1. issue all raw y[b] loads immediately (no dependencies, no guards)
    float raw[16];
#pragma unroll
    for (int k = 0; k < 16; ++k) {
        int r = k * 256 + tid;           // 0..4095 = ci*512 + id*64 + ih*8 + iw
        raw[k] = yin[((size_t)(b * 8) << 9) + r];
    }

    // 2. stats -> LDS; 3. zero slab (both overlap the loads above)
    if (tid < 16) sstat[tid] = stats_in[tid];
    for (int i = tid; i < 5760; i += 256) slab[i] = 0.0f;
    __syncthreads();

    if (tid < 8) {
        float S = sstat[tid], Q = sstat[8 + tid];
        float m  = S * (1.0f / 2048.0f);
        float vv = Q * (1.0f / 2048.0f) - m * m;
        float rs = rsqrtf(vv + 1e-5f);
        float sc = g[tid] * rs;
        sscale[tid] = sc;
        sshift[tid] = bet[tid] - m * sc;
    }
    __syncthreads();

    // 4. scatter BN+ELU'd values into the padded slab
#pragma unroll
    for (int k = 0; k < 16; ++k) {
        int r  = k * 256 + tid;
        int ci = r >> 9, rem = r & 511;
        int id = rem >> 6, ih = (rem >> 3) & 7, iw = rem & 7;
        int kd = id - od + 2;
        if ((unsigned)kd < 5u) {
            float t = fmaf(raw[k], sscale[ci], sshift[ci]);
            slab[ci * 720 + kd * 144 + (ih + 2) * 12 + (iw + 2)] =
                t > 0.0f ? t : __expf(t) - 1.0f;
        }
    }
    __syncthreads();

    // 5. conv: thread = (ow, oh, ciq); ciq covers 2 ci
    int ow = tid & 7, oh = (tid >> 3) & 7, ciq = tid >> 6;
    float s = 0.0f;
#pragma unroll
    for (int c2 = 0; c2 < 2; ++c2) {
        int ci = ciq * 2 + c2;
        const float* sl = slab + ci * 720;
        const float* wc = w + (size_t)(co * 8 + ci) * 125;
#pragma unroll
        for (int kd = 0; kd < 5; ++kd) {
#pragma unroll
            for (int kh = 0; kh < 5; ++kh) {
                const float* row = sl + kd * 144 + (oh + kh) * 12 + ow;
                const float* wr = wc + kd * 25 + kh * 5;
#pragma unroll
                for (int kw = 0; kw < 5; ++kw) s = fmaf(row[kw], wr[kw], s);
            }
        }
    }
    sred[tid] = s;
    __syncthreads();
    if (tid < 64) {
        float tot = sred[tid] + sred[64+tid] + sred[128+tid] + sred[192+tid] + bias[co];
        yout[(size_t)(b * 8 + co) * 512 + od * 64 + tid] = tot;
        float sum = tot, sq = tot * tot;
#pragma unroll
        for (int o = 32; o > 0; o >>= 1) {
            sum += __shfl_down(sum, o, 64);
            sq  += __shfl_down(sq,  o, 64);
        }
        if (tid == 0) { atomicAdd(&stats_out[co], sum); atomicAdd(&stats_out[8 + co], sq); }
    }
}

// ---------------------------------------------------------------------------
// final BN + ELU -> d_out
// ---------------------------------------------------------------------------
__global__ __launch_bounds__(256)
void bn_final_kernel(const float* __restrict__ yin,
                     const float* __restrict__ g, const float* __restrict__ bet,
                     const float* __restrict__ stats_in, float* __restrict__ outp)
{
    int i = blockIdx.x * 256 + threadIdx.x;   // 16384 total
    float v = yin[i];                          // issue load first
    int c = (i >> 9) & 7;
    float S = stats_in[c], Q = stats_in[8 + c];
    float m  = S * (1.0f / 2048.0f);
    float vv = Q * (1.0f / 2048.0f) - m * m;
    float rs = rsqrtf(vv + 1e-5f);
    float sc = g[c] * rs;
    float sh = bet[c] - m * sc;
    float t = fmaf(v, sc, sh);
    outp[i] = t > 0.0f ? t : __expf(t) - 1.0f;
}

// ---------------------------------------------------------------------------
extern "C" void kernel_launch(void* const* d_in, const int* in_sizes, int n_in,
                              void* d_out, int out_size, void* d_ws, size_t ws_size,
                              hipStream_t stream)
{
    const float* goals       = (const float*)d_in[0];
    const float* inputs      = (const float*)d_in[1];
    const float* backgrounds = (const float*)d_in[2];
    const float* W1 = (const float*)d_in[3];
    const float* b1 = (const float*)d_in[4];
    const float* W2 = (const float*)d_in[5];
    const float* b2 = (const float*)d_in[6];
    const float* W3 = (const float*)d_in[7];
    const float* b3 = (const float*)d_in[8];
    const float* conv1_w = (const float*)d_in[9];
    const float* conv1_b = (const float*)d_in[10];
    const float* bn1_g   = (const float*)d_in[11];
    const float* bn1_b   = (const float*)d_in[12];
    const float* convs_w = (const float*)d_in[13];
    const float* convs_b = (const float*)d_in[14];
    const float* bns_g   = (const float*)d_in[15];
    const float* bns_b   = (const float*)d_in[16];

    // --- pick (K replicas, S segments) to fit the workspace -----------------
    long ws_floats = (long)(ws_size / 4);
    long fixed = SCENE_FLOATS + 2L * 16384 + 128;
    static const int plans[][2] = {
        {42,1},{42,2},{42,4},{24,4},{21,6},{16,8},{8,12},{4,16},{2,32},{1,64}};
    int K = 1, S = 64;
    for (int pi = 0; pi < 10; ++pi) {
        int pk = plans[pi][0], ps = plans[pi][1];
        long mseg = (NPTS + ps - 1) / ps;
        long need = 60L * mseg + (long)pk * SCENE_FLOATS + fixed;
        if (need <= ws_floats) { K = pk; S = ps; break; }
    }
    int Mseg = (NPTS + S - 1) / S;

    float*  wsp     = (float*)d_ws;
    float4* vals    = (float4*)wsp;                          // 12*Mseg float4
    int*    cells   = (int*)(wsp + 48L * Mseg);              // 12*Mseg ints
    float*  scenesR = wsp + 60L * Mseg;                      // K * SCENE_FLOATS
    float*  scenes  = scenesR + (size_t)K * SCENE_FLOATS;    // 162000
    float*  yA      = scenes + SCENE_FLOATS;                 // 16384
    float*  yB      = yA + 16384;                            // 16384
    float*  stats   = yB + 16384;                            // 7*16 floats (+pad)

    for (int s = 0; s < S; ++s) {
        int s0 = s * Mseg;
        int m  = min(Mseg, NPTS - s0);
        dim3 agrid((m + 255) / 256, B, 3);
        mlp_kernel<<<agrid, 256, 0, stream>>>(inputs, goals, backgrounds,
                                              W1, b1, W2, b2, W3, b3,
                                              vals, cells, stats, s0, m);
        dim3 bgrid(K, B, 3);
        scatter_kernel<<<bgrid, 512, 0, stream>>>(vals, cells, scenesR, K, m,
                                                  s > 0 ? 1 : 0);
    }

    reduce_kernel<<<(SCENE_FLOATS + 255) / 256, 256, 0, stream>>>(scenesR, scenes, K);

    conv1_kernel<<<256, 256, 0, stream>>>(scenes, conv1_w, conv1_b, yA, stats);

    const float* cur = yA;
    float* nxt = yB;
    for (int i = 0; i < 6; ++i) {
        const float* g   = (i == 0) ? bn1_g : (bns_g + (i - 1) * 8);
        const float* bet = (i == 0) ? bn1_b : (bns_b + (i - 1) * 8);
        conv_s_kernel<<<256, 256, 0, stream>>>(
            cur, convs_w + (size_t)i * 8000, convs_b + i * 8,
            g, bet, stats + i * 16, nxt, stats + (i + 1) * 16);
        const float* tmp = cur; cur = nxt; nxt = (float*)tmp;
    }

    bn_final_kernel<<<64, 256, 0, stream>>>(cur, bns_g + 5 * 8, bns_b + 5 * 8,
                                            stats + 6 * 16, (float*)d_out);
}

// Round 7
// 280.935 us; speedup vs baseline: 1.9284x; 1.0740x over previous
//
#include <hip/hip_runtime.h>
#include <math.h>

#define B 4
#define NPTS 300000
#define G 15
#define G3 3375
#define PAIR_FLOATS (4*G3)       // 13500 floats: one (b,set) grid, 4 channels
#define SCENE_FLOATS (B*12*G3)   // 162000

__device__ __forceinline__ float eluf(float v) {
    return v > 0.0f ? v : __expf(v) - 1.0f;
}

// ---------------------------------------------------------------------------
// Phase A: pure MLP. One point per thread, NO loop, NO atomics, NO LDS.
// Weights consumed straight from the scalar cache (24 VGPR codegen).
// Block (0,0,0) also zeroes the stats buffer (saves a memset dispatch).
// ---------------------------------------------------------------------------
__global__ __launch_bounds__(256)
void mlp_kernel(const float* __restrict__ P0,   // inputs  (set 0)
                const float* __restrict__ P1,   // goals   (set 1)
                const float* __restrict__ P2,   // backgrounds (set 2)
                const float* __restrict__ W1, const float* __restrict__ b1,
                const float* __restrict__ W2, const float* __restrict__ b2,
                const float* __restrict__ W3, const float* __restrict__ b3,
                float4* __restrict__ vals, int* __restrict__ cells,
                float* __restrict__ stats,
                int s0, int m)
{
    if (blockIdx.x == 0 && blockIdx.y == 0 && blockIdx.z == 0 && threadIdx.x < 128)
        stats[threadIdx.x] = 0.0f;

    int b   = blockIdx.y;
    int set = blockIdx.z;
    int i   = blockIdx.x * 256 + threadIdx.x;
    if (i >= m) return;
    const float* P = (set == 0) ? P0 : ((set == 1) ? P1 : P2);

    const float* p = P + ((size_t)b * NPTS + (size_t)(s0 + i)) * 3;
    float px = p[0], py = p[1], pz = p[2];

    const float HI = 14.9999f;  // GZ - 1e-4
    float cx = floorf(fminf(fmaxf(px, 0.0f), HI));
    float cy = floorf(fminf(fmaxf(py, 0.0f), HI));
    float cz = floorf(fminf(fmaxf(pz, 0.0f), HI));

    float x[12];
    x[0] = px - (cx + 0.5f); x[1] = py - (cy + 0.5f); x[2] = pz - (cz + 0.5f);
    x[3] = px - cx;          x[4] = py - cy;          x[5] = pz - cz;
    x[6] = px - (cx + 1.0f); x[7] = py - (cy + 1.0f); x[8] = pz - (cz + 1.0f);
    x[9]  = sqrtf(x[0]*x[0] + x[1]*x[1] + x[2]*x[2]);
    x[10] = sqrtf(x[3]*x[3] + x[4]*x[4] + x[5]*x[5]);
    x[11] = sqrtf(x[6]*x[6] + x[7]*x[7] + x[8]*x[8]);

    float h1[16];
#pragma unroll
    for (int j = 0; j < 16; ++j) {
        float s = b1[j];
#pragma unroll
        for (int k = 0; k < 12; ++k) s = fmaf(x[k], W1[k*16 + j], s);
        h1[j] = eluf(s);
    }
    float h2[16];
#pragma unroll
    for (int j = 0; j < 16; ++j) {
        float s = b2[j];
#pragma unroll
        for (int k = 0; k < 16; ++k) s = fmaf(h1[k], W2[k*16 + j], s);
        h2[j] = eluf(s);
    }
    float o[4];
#pragma unroll
    for (int j = 0; j < 4; ++j) {
        float s = b3[j];
#pragma unroll
        for (int k = 0; k < 16; ++k) s = fmaf(h2[k], W3[k*4 + j], s);
        o[j] = s;
    }

    int cell = (((int)cx) * G + (int)cy) * G + (int)cz;
    int pair = b * 3 + set;
    vals [(size_t)pair * m + i] = make_float4(o[0], o[1], o[2], o[3]);
    cells[(size_t)pair * m + i] = cell;
}

// ---------------------------------------------------------------------------
// Phase B: scatter-max into a PRIVATE LDS grid (54 KB), flush with plain
// stores into this block's replica. 512 threads for latency hiding.
// grid: (K, B, 3); block 512.
// ---------------------------------------------------------------------------
__global__ __launch_bounds__(512)
void scatter_kernel(const float4* __restrict__ vals,
                    const int* __restrict__ cells,
                    float* __restrict__ scenesR, int K, int m, int carry)
{
    __shared__ unsigned sg[PAIR_FLOATS];   // uint-ordered positive floats

    int rep = blockIdx.x;
    int b   = blockIdx.y;
    int set = blockIdx.z;
    int pair = b * 3 + set;
    float* myrep = scenesR + ((size_t)pair * K + rep) * PAIR_FLOATS;

    if (carry) {
        for (int i = threadIdx.x; i < PAIR_FLOATS; i += 512)
            sg[i] = __float_as_uint(myrep[i]);     // values are >= 0
    } else {
        for (int i = threadIdx.x; i < PAIR_FLOATS; i += 512)
            sg[i] = 0u;
    }
    __syncthreads();

    int chunk = (m + K - 1) / K;
    int start = rep * chunk;
    int end   = min(m, start + chunk);
    const float4* v = vals  + (size_t)pair * m;
    const int*    c = cells + (size_t)pair * m;

    for (int i = start + (int)threadIdx.x; i < end; i += 512) {
        float4 o = v[i];
        int cell = c[i];
        if (o.x > 0.0f) atomicMax(&sg[          cell], __float_as_uint(o.x));
        if (o.y > 0.0f) atomicMax(&sg[    G3 + cell], __float_as_uint(o.y));
        if (o.z > 0.0f) atomicMax(&sg[2 * G3 + cell], __float_as_uint(o.z));
        if (o.w > 0.0f) atomicMax(&sg[3 * G3 + cell], __float_as_uint(o.w));
    }
    __syncthreads();

    for (int i = threadIdx.x; i < PAIR_FLOATS; i += 512)
        myrep[i] = __uint_as_float(sg[i]);
}

// ---------------------------------------------------------------------------
// max-reduce K replicas per pair -> scenes [B,12,G3]
// ---------------------------------------------------------------------------
__global__ __launch_bounds__(256)
void reduce_kernel(const float* __restrict__ scenesR, float* __restrict__ scenes,
                   int K)
{
    int t = blockIdx.x * 256 + threadIdx.x;
    if (t >= SCENE_FLOATS) return;
    int pair = t / PAIR_FLOATS;
    int j    = t - pair * PAIR_FLOATS;
    const float* src = scenesR + (size_t)pair * K * PAIR_FLOATS + j;
    float mx = 0.0f;
    for (int r = 0; r < K; ++r)
        mx = fmaxf(mx, src[(size_t)r * PAIR_FLOATS]);
    scenes[t] = mx;
}

// ---------------------------------------------------------------------------
// conv1: scenes [B,12,15,15,15] -> y0 [B,8,8,8,8] (raw conv+bias) + stats0
// v2: 768 threads (12 waves) = (ci, oh, ow); ONE ci per thread -> 125-FMA
// serial chain (was 375) and 3x the waves for latency hiding.
// grid: (b,co,od)=256 blocks.
// ---------------------------------------------------------------------------
__global__ __launch_bounds__(768)
void conv1_kernel(const float* __restrict__ scenes,
                  const float* __restrict__ w,    // [8,12,125]
                  const float* __restrict__ bias, // [8]
                  float* __restrict__ y, float* __restrict__ stats)
{
    __shared__ float sred[768];
    int bx = blockIdx.x;
    int od = bx & 7, co = (bx >> 3) & 7, b = bx >> 6;
    int tid = threadIdx.x;
    int ow = tid & 7, oh = (tid >> 3) & 7, ci = tid >> 6;   // ci in 0..11

    const float* sc = scenes + (size_t)(b * 12 + ci) * G3;
    const float* wc = w + (size_t)(co * 12 + ci) * 125;
    float s = 0.0f;
#pragma unroll
    for (int kd = 0; kd < 5; ++kd) {
        int id = od * 2 - 2 + kd;
        if ((unsigned)id >= (unsigned)G) continue;   // block-uniform
#pragma unroll
        for (int kh = 0; kh < 5; ++kh) {
            int ih = oh * 2 - 2 + kh;
            bool hok = (unsigned)ih < (unsigned)G;
#pragma unroll
            for (int kw = 0; kw < 5; ++kw) {
                int iw = ow * 2 - 2 + kw;
                if (hok && (unsigned)iw < (unsigned)G)
                    s = fmaf(sc[(id * G + ih) * G + iw], wc[kd*25 + kh*5 + kw], s);
            }
        }
    }
    sred[tid] = s;
    __syncthreads();
    if (tid < 64) {
        float tot = bias[co];
#pragma unroll
        for (int g2 = 0; g2 < 12; ++g2) tot += sred[g2 * 64 + tid];
        y[(size_t)(b * 8 + co) * 512 + od * 64 + tid] = tot;
        float sum = tot, sq = tot * tot;
#pragma unroll
        for (int o = 32; o > 0; o >>= 1) {
            sum += __shfl_down(sum, o, 64);
            sq  += __shfl_down(sq,  o, 64);
        }
        if (tid == 0) { atomicAdd(&stats[co], sum); atomicAdd(&stats[8 + co], sq); }
    }
}

// ---------------------------------------------------------------------------
// conv_s: BN(stats_in,g,beta)+ELU applied to yin on the fly, then 5^3 conv.
// v3: 512 threads (8 waves) = (ci, oh, ow); ONE ci per thread -> 125-FMA
// serial chain (was 250) and 2x the waves. Raw y loads issued first,
// stats/rsqrt + slab-zero overlap under them.
// grid: (b,co,od)=256 blocks.
// ---------------------------------------------------------------------------
__global__ __launch_bounds__(512)
void conv_s_kernel(const float* __restrict__ yin,
                   const float* __restrict__ w,     // [8,8,125] this layer
                   const float* __restrict__ bias,  // [8]
                   const float* __restrict__ g, const float* __restrict__ bet,
                   const float* __restrict__ stats_in,
                   float* __restrict__ yout, float* __restrict__ stats_out)
{
    __shared__ float slab[8 * 5 * 144];   // [ci][kd][12][12], zero-padded
    __shared__ float sstat[16], sscale[8], sshift[8];
    __shared__ float sred[512];

    int bx = blockIdx.x;
    int od = bx & 7, co = (bx >> 3) & 7, b = bx >> 6;
    int tid = threadIdx.x;

    // 1. issue all raw y[b] loads immediately (no dependencies, no guards)
    float raw[8];
#pragma unroll
    for (int k = 0; k < 8; ++k) {
        int r = k * 512 + tid;           // 0..4095 = ci*512 + id*64 + ih*8 + iw
        raw[k] = yin[((size_t)(b * 8) << 9) + r];
    }

    // 2. stats -> LDS; 3. zero slab (both overlap the loads above)
    if (tid < 16) sstat[tid] = stats_in[tid];
    for (int i = tid; i < 5760; i += 512) slab[i] = 0.0f;
    __syncthreads();

    if (tid < 8) {
        float S = sstat[tid], Q = sstat[8 + tid];
        float m  = S * (1.0f / 2048.0f);
        float vv = Q * (1.0f / 2048.0f) - m * m;
        float rs = rsqrtf(vv + 1e-5f);
        float sc = g[tid] * rs;
        sscale[tid] = sc;
        sshift[tid] = bet[tid] - m * sc;
    }
    __syncthreads();

    // 4. scatter BN+ELU'd values into the padded slab
#pragma unroll
    for (int k = 0; k < 8; ++k) {
        int r  = k * 512 + tid;
        int ci = r >> 9, rem = r & 511;
        int id = rem >> 6, ih = (rem >> 3) & 7, iw = rem & 7;
        int kd = id - od + 2;
        if ((unsigned)kd < 5u) {
            float t = fmaf(raw[k], sscale[ci], sshift[ci]);
            slab[ci * 720 + kd * 144 + (ih + 2) * 12 + (iw + 2)] =
                t > 0.0f ? t : __expf(t) - 1.0f;
        }
    }
    __syncthreads();

    // 5. conv: thread = (ow, oh, ci); one ci each
    int ow = tid & 7, oh = (tid >> 3) & 7, ci = tid >> 6;
    const float* sl = slab + ci * 720;
    const float* wc = w + (size_t)(co * 8 + ci) * 125;
    float s = 0.0f;
#pragma unroll
    for (int kd = 0; kd < 5; ++kd) {
#pragma unroll
        for (int kh = 0; kh < 5; ++kh) {
            const float* row = sl + kd * 144 + (oh + kh) * 12 + ow;
            const float* wr = wc + kd * 25 + kh * 5;
#pragma unroll
            for (int kw = 0; kw < 5; ++kw) s = fmaf(row[kw], wr[kw], s);
        }
    }
    sred[tid] = s;
    __syncthreads();
    if (tid < 64) {
        float tot = bias[co];
#pragma unroll
        for (int g2 = 0; g2 < 8; ++g2) tot += sred[g2 * 64 + tid];
        yout[(size_t)(b * 8 + co) * 512 + od * 64 + tid] = tot;
        float sum = tot, sq = tot * tot;
#pragma unroll
        for (int o = 32; o > 0; o >>= 1) {
            sum += __shfl_down(sum, o, 64);
            sq  += __shfl_down(sq,  o, 64);
        }
        if (tid == 0) { atomicAdd(&stats_out[co], sum); atomicAdd(&stats_out[8 + co], sq); }
    }
}

// ---------------------------------------------------------------------------
// final BN + ELU -> d_out
// ---------------------------------------------------------------------------
__global__ __launch_bounds__(256)
void bn_final_kernel(const float* __restrict__ yin,
                     const float* __restrict__ g, const float* __restrict__ bet,
                     const float* __restrict__ stats_in, float* __restrict__ outp)
{
    int i = blockIdx.x * 256 + threadIdx.x;   // 16384 total
    float v = yin[i];                          // issue load first
    int c = (i >> 9) & 7;
    float S = stats_in[c], Q = stats_in[8 + c];
    float m  = S * (1.0f / 2048.0f);
    float vv = Q * (1.0f / 2048.0f) - m * m;
    float rs = rsqrtf(vv + 1e-5f);
    float sc = g[c] * rs;
    float sh = bet[c] - m * sc;
    float t = fmaf(v, sc, sh);
    outp[i] = t > 0.0f ? t : __expf(t) - 1.0f;
}

// ---------------------------------------------------------------------------
extern "C" void kernel_launch(void* const* d_in, const int* in_sizes, int n_in,
                              void* d_out, int out_size, void* d_ws, size_t ws_size,
                              hipStream_t stream)
{
    const float* goals       = (const float*)d_in[0];
    const float* inputs      = (const float*)d_in[1];
    const float* backgrounds = (const float*)d_in[2];
    const float* W1 = (const float*)d_in[3];
    const float* b1 = (const float*)d_in[4];
    const float* W2 = (const float*)d_in[5];
    const float* b2 = (const float*)d_in[6];
    const float* W3 = (const float*)d_in[7];
    const float* b3 = (const float*)d_in[8];
    const float* conv1_w = (const float*)d_in[9];
    const float* conv1_b = (const float*)d_in[10];
    const float* bn1_g   = (const float*)d_in[11];
    const float* bn1_b   = (const float*)d_in[12];
    const float* convs_w = (const float*)d_in[13];
    const float* convs_b = (const float*)d_in[14];
    const float* bns_g   = (const float*)d_in[15];
    const float* bns_b   = (const float*)d_in[16];

    // --- pick (K replicas, S segments) to fit the workspace -----------------
    long ws_floats = (long)(ws_size / 4);
    long fixed = SCENE_FLOATS + 2L * 16384 + 128;
    static const int plans[][2] = {
        {42,1},{42,2},{42,4},{24,4},{21,6},{16,8},{8,12},{4,16},{2,32},{1,64}};
    int K = 1, S = 64;
    for (int pi = 0; pi < 10; ++pi) {
        int pk = plans[pi][0], ps = plans[pi][1];
        long mseg = (NPTS + ps - 1) / ps;
        long need = 60L * mseg + (long)pk * SCENE_FLOATS + fixed;
        if (need <= ws_floats) { K = pk; S = ps; break; }
    }
    int Mseg = (NPTS + S - 1) / S;

    float*  wsp     = (float*)d_ws;
    float4* vals    = (float4*)wsp;                          // 12*Mseg float4
    int*    cells   = (int*)(wsp + 48L * Mseg);              // 12*Mseg ints
    float*  scenesR = wsp + 60L * Mseg;                      // K * SCENE_FLOATS
    float*  scenes  = scenesR + (size_t)K * SCENE_FLOATS;    // 162000
    float*  yA      = scenes + SCENE_FLOATS;                 // 16384
    float*  yB      = yA + 16384;                            // 16384
    float*  stats   = yB + 16384;                            // 7*16 floats (+pad)

    for (int s = 0; s < S; ++s) {
        int s0 = s * Mseg;
        int m  = min(Mseg, NPTS - s0);
        dim3 agrid((m + 255) / 256, B, 3);
        mlp_kernel<<<agrid, 256, 0, stream>>>(inputs, goals, backgrounds,
                                              W1, b1, W2, b2, W3, b3,
                                              vals, cells, stats, s0, m);
        dim3 bgrid(K, B, 3);
        scatter_kernel<<<bgrid, 512, 0, stream>>>(vals, cells, scenesR, K, m,
                                                  s > 0 ? 1 : 0);
    }

    reduce_kernel<<<(SCENE_FLOATS + 255) / 256, 256, 0, stream>>>(scenesR, scenes, K);

    conv1_kernel<<<256, 768, 0, stream>>>(scenes, conv1_w, conv1_b, yA, stats);

    const float* cur = yA;
    float* nxt = yB;
    for (int i = 0; i < 6; ++i) {
        const float* g   = (i == 0) ? bn1_g : (bns_g + (i - 1) * 8);
        const float* bet = (i == 0) ? bn1_b : (bns_b + (i - 1) * 8);
        conv_s_kernel<<<256, 512, 0, stream>>>(
            cur, convs_w + (size_t)i * 8000, convs_b + i * 8,
            g, bet, stats + i * 16, nxt, stats + (i + 1) * 16);
        const float* tmp = cur; cur = nxt; nxt = (float*)tmp;
    }

    bn_final_kernel<<<64, 256, 0, stream>>>(cur, bns_g + 5 * 8, bns_b + 5 * 8,
                                            stats + 6 * 16, (float*)d_out);
}

// Round 8
// 279.701 us; speedup vs baseline: 1.9369x; 1.0044x over previous
//
#include <hip/hip_runtime.h>
#include <math.h>

#define B 4
#define NPTS 300000
#define G 15
#define G3 3375
#define PAIR_FLOATS (4*G3)       // 13500 floats: one (b,set) grid, 4 channels
#define SCENE_FLOATS (B*12*G3)   // 162000

typedef float v2f __attribute__((ext_vector_type(2)));

__device__ __forceinline__ float eluf(float v) {
    return v > 0.0f ? v : __expf(v) - 1.0f;
}

// ---------------------------------------------------------------------------
// Phase A: pure MLP, one point per thread. fp32 math paired into float2
// accumulators so the backend can emit v_pk_fma_f32 (gfx950 packed fp32):
// weight PAIR is the single wave-uniform SGPR-pair operand, x broadcast in
// a VGPR pair. Halves the 512-FMA issue count if selected.
// Block (0,0,0) also zeroes the stats buffer (saves a memset dispatch).
// ---------------------------------------------------------------------------
__global__ __launch_bounds__(256)
void mlp_kernel(const float* __restrict__ P0,   // inputs  (set 0)
                const float* __restrict__ P1,   // goals   (set 1)
                const float* __restrict__ P2,   // backgrounds (set 2)
                const float* __restrict__ W1, const float* __restrict__ b1,
                const float* __restrict__ W2, const float* __restrict__ b2,
                const float* __restrict__ W3, const float* __restrict__ b3,
                float4* __restrict__ vals, unsigned short* __restrict__ cells,
                float* __restrict__ stats,
                int s0, int m)
{
    if (blockIdx.x == 0 && blockIdx.y == 0 && blockIdx.z == 0 && threadIdx.x < 128)
        stats[threadIdx.x] = 0.0f;

    int b   = blockIdx.y;
    int set = blockIdx.z;
    int i   = blockIdx.x * 256 + threadIdx.x;
    if (i >= m) return;
    const float* P = (set == 0) ? P0 : ((set == 1) ? P1 : P2);

    const float* p = P + ((size_t)b * NPTS + (size_t)(s0 + i)) * 3;
    float px = p[0], py = p[1], pz = p[2];

    const float HI = 14.9999f;  // GZ - 1e-4
    float cx = floorf(fminf(fmaxf(px, 0.0f), HI));
    float cy = floorf(fminf(fmaxf(py, 0.0f), HI));
    float cz = floorf(fminf(fmaxf(pz, 0.0f), HI));

    float x[12];
    x[0] = px - (cx + 0.5f); x[1] = py - (cy + 0.5f); x[2] = pz - (cz + 0.5f);
    x[3] = px - cx;          x[4] = py - cy;          x[5] = pz - cz;
    x[6] = px - (cx + 1.0f); x[7] = py - (cy + 1.0f); x[8] = pz - (cz + 1.0f);
    x[9]  = sqrtf(x[0]*x[0] + x[1]*x[1] + x[2]*x[2]);
    x[10] = sqrtf(x[3]*x[3] + x[4]*x[4] + x[5]*x[5]);
    x[11] = sqrtf(x[6]*x[6] + x[7]*x[7] + x[8]*x[8]);

    const v2f* W1v = (const v2f*)W1;   // [12][8] pairs
    const v2f* W2v = (const v2f*)W2;   // [16][8] pairs
    const v2f* W3v = (const v2f*)W3;   // [16][2] pairs
    const v2f* b1v = (const v2f*)b1;
    const v2f* b2v = (const v2f*)b2;
    const v2f* b3v = (const v2f*)b3;

    // layer 1: 12 -> 16  (96 pk-fma)
    float h1[16];
#pragma unroll
    for (int j2 = 0; j2 < 8; ++j2) {
        v2f s = b1v[j2];
#pragma unroll
        for (int k = 0; k < 12; ++k) {
            v2f xb; xb.x = x[k]; xb.y = x[k];
            s = xb * W1v[k * 8 + j2] + s;      // contract=fast -> pk_fma
        }
        h1[2*j2]   = eluf(s.x);
        h1[2*j2+1] = eluf(s.y);
    }
    // layer 2: 16 -> 16  (128 pk-fma)
    float h2[16];
#pragma unroll
    for (int j2 = 0; j2 < 8; ++j2) {
        v2f s = b2v[j2];
#pragma unroll
        for (int k = 0; k < 16; ++k) {
            v2f xb; xb.x = h1[k]; xb.y = h1[k];
            s = xb * W2v[k * 8 + j2] + s;
        }
        h2[2*j2]   = eluf(s.x);
        h2[2*j2+1] = eluf(s.y);
    }
    // layer 3: 16 -> 4  (32 pk-fma)
    v2f o01 = b3v[0], o23 = b3v[1];
#pragma unroll
    for (int k = 0; k < 16; ++k) {
        v2f xb; xb.x = h2[k]; xb.y = h2[k];
        o01 = xb * W3v[k * 2 + 0] + o01;
        o23 = xb * W3v[k * 2 + 1] + o23;
    }

    int cell = (((int)cx) * G + (int)cy) * G + (int)cz;
    int pair = b * 3 + set;
    vals [(size_t)pair * m + i] = make_float4(o01.x, o01.y, o23.x, o23.y);
    cells[(size_t)pair * m + i] = (unsigned short)cell;
}

// ---------------------------------------------------------------------------
// Phase B: scatter-max into a PRIVATE LDS grid (54 KB), flush with plain
// stores into this block's replica. 512 threads for latency hiding.
// grid: (K, B, 3); block 512.
// ---------------------------------------------------------------------------
__global__ __launch_bounds__(512)
void scatter_kernel(const float4* __restrict__ vals,
                    const unsigned short* __restrict__ cells,
                    float* __restrict__ scenesR, int K, int m, int carry)
{
    __shared__ unsigned sg[PAIR_FLOATS];   // uint-ordered positive floats

    int rep = blockIdx.x;
    int b   = blockIdx.y;
    int set = blockIdx.z;
    int pair = b * 3 + set;
    float* myrep = scenesR + ((size_t)pair * K + rep) * PAIR_FLOATS;

    if (carry) {
        for (int i = threadIdx.x; i < PAIR_FLOATS; i += 512)
            sg[i] = __float_as_uint(myrep[i]);     // values are >= 0
    } else {
        for (int i = threadIdx.x; i < PAIR_FLOATS; i += 512)
            sg[i] = 0u;
    }
    __syncthreads();

    int chunk = (m + K - 1) / K;
    int start = rep * chunk;
    int end   = min(m, start + chunk);
    const float4*         v = vals  + (size_t)pair * m;
    const unsigned short* c = cells + (size_t)pair * m;

    for (int i = start + (int)threadIdx.x; i < end; i += 512) {
        float4 o = v[i];
        int cell = c[i];
        if (o.x > 0.0f) atomicMax(&sg[          cell], __float_as_uint(o.x));
        if (o.y > 0.0f) atomicMax(&sg[    G3 + cell], __float_as_uint(o.y));
        if (o.z > 0.0f) atomicMax(&sg[2 * G3 + cell], __float_as_uint(o.z));
        if (o.w > 0.0f) atomicMax(&sg[3 * G3 + cell], __float_as_uint(o.w));
    }
    __syncthreads();

    for (int i = threadIdx.x; i < PAIR_FLOATS; i += 512)
        myrep[i] = __uint_as_float(sg[i]);
}

// ---------------------------------------------------------------------------
// max-reduce K replicas per pair -> scenes [B,12,G3]
// ---------------------------------------------------------------------------
__global__ __launch_bounds__(256)
void reduce_kernel(const float* __restrict__ scenesR, float* __restrict__ scenes,
                   int K)
{
    int t = blockIdx.x * 256 + threadIdx.x;
    if (t >= SCENE_FLOATS) return;
    int pair = t / PAIR_FLOATS;
    int j    = t - pair * PAIR_FLOATS;
    const float* src = scenesR + (size_t)pair * K * PAIR_FLOATS + j;
    float mx = 0.0f;
    for (int r = 0; r < K; ++r)
        mx = fmaxf(mx, src[(size_t)r * PAIR_FLOATS]);
    scenes[t] = mx;
}

// ---------------------------------------------------------------------------
// conv1: scenes [B,12,15,15,15] -> y0 [B,8,8,8,8] (raw conv+bias) + stats0
// 768 threads (12 waves) = (ci, oh, ow); ONE ci per thread -> 125-FMA chain.
// grid: (b,co,od)=256 blocks.
// ---------------------------------------------------------------------------
__global__ __launch_bounds__(768)
void conv1_kernel(const float* __restrict__ scenes,
                  const float* __restrict__ w,    // [8,12,125]
                  const float* __restrict__ bias, // [8]
                  float* __restrict__ y, float* __restrict__ stats)
{
    __shared__ float sred[768];
    int bx = blockIdx.x;
    int od = bx & 7, co = (bx >> 3) & 7, b = bx >> 6;
    int tid = threadIdx.x;
    int ow = tid & 7, oh = (tid >> 3) & 7, ci = tid >> 6;   // ci in 0..11

    const float* sc = scenes + (size_t)(b * 12 + ci) * G3;
    const float* wc = w + (size_t)(co * 12 + ci) * 125;
    float s = 0.0f;
#pragma unroll
    for (int kd = 0; kd < 5; ++kd) {
        int id = od * 2 - 2 + kd;
        if ((unsigned)id >= (unsigned)G) continue;   // block-uniform
#pragma unroll
        for (int kh = 0; kh < 5; ++kh) {
            int ih = oh * 2 - 2 + kh;
            bool hok = (unsigned)ih < (unsigned)G;
#pragma unroll
            for (int kw = 0; kw < 5; ++kw) {
                int iw = ow * 2 - 2 + kw;
                if (hok && (unsigned)iw < (unsigned)G)
                    s = fmaf(sc[(id * G + ih) * G + iw], wc[kd*25 + kh*5 + kw], s);
            }
        }
    }
    sred[tid] = s;
    __syncthreads();
    if (tid < 64) {
        float tot = bias[co];
#pragma unroll
        for (int g2 = 0; g2 < 12; ++g2) tot += sred[g2 * 64 + tid];
        y[(size_t)(b * 8 + co) * 512 + od * 64 + tid] = tot;
        float sum = tot, sq = tot * tot;
#pragma unroll
        for (int o = 32; o > 0; o >>= 1) {
            sum += __shfl_down(sum, o, 64);
            sq  += __shfl_down(sq,  o, 64);
        }
        if (tid == 0) { atomicAdd(&stats[co], sum); atomicAdd(&stats[8 + co], sq); }
    }
}

// ---------------------------------------------------------------------------
// conv_s: BN(stats_in,g,beta)+ELU applied to yin on the fly, then 5^3 conv.
// 512 threads (8 waves) = (ci, oh, ow); ONE ci per thread -> 125-FMA chain.
// Raw y loads issued first; stats/rsqrt + slab-zero overlap under them.
// grid: (b,co,od)=256 blocks.
// ---------------------------------------------------------------------------
__global__ __launch_bounds__(512)
void conv_s_kernel(const float* __restrict__ yin,
                   const float* __restrict__ w,     // [8,8,125] this layer
                   const float* __restrict__ bias,  // [8]
                   const float* __restrict__ g, const float* __restrict__ bet,
                   const float* __restrict__ stats_in,
                   float* __restrict__ yout, float* __restrict__ stats_out)
{
    __shared__ float slab[8 * 5 * 144];   // [ci][kd][12][12], zero-padded
    __shared__ float sstat[16], sscale[8], sshift[8];
    __shared__ float sred[512];

    int bx = blockIdx.x;
    int od = bx & 7, co = (bx >> 3) & 7, b = bx >> 6;
    int tid = threadIdx.x;

    // 1. issue all raw y[b] loads immediately (no dependencies, no guards)
    float raw[8];
#pragma unroll
    for (int k = 0; k < 8; ++k) {
        int r = k * 512 + tid;           // 0..4095 = ci*512 + id*64 + ih*8 + iw
        raw[k] = yin[((size_t)(b * 8) << 9) + r];
    }

    // 2. stats -> LDS; 3. zero slab (both overlap the loads above)
    if (tid < 16) sstat[tid] = stats_in[tid];
    for (int i = tid; i < 5760; i += 512) slab[i] = 0.0f;
    __syncthreads();

    if (tid < 8) {
        float S = sstat[tid], Q = sstat[8 + tid];
        float m  = S * (1.0f / 2048.0f);
        float vv = Q * (1.0f / 2048.0f) - m * m;
        float rs = rsqrtf(vv + 1e-5f);
        float sc = g[tid] * rs;
        sscale[tid] = sc;
        sshift[tid] = bet[tid] - m * sc;
    }
    __syncthreads();

    // 4. scatter BN+ELU'd values into the padded slab
#pragma unroll
    for (int k = 0; k < 8; ++k) {
        int r  = k * 512 + tid;
        int ci = r >> 9, rem = r & 511;
        int id = rem >> 6, ih = (rem >> 3) & 7, iw = rem & 7;
        int kd = id - od + 2;
        if ((unsigned)kd < 5u) {
            float t = fmaf(raw[k], sscale[ci], sshift[ci]);
            slab[ci * 720 + kd * 144 + (ih + 2) * 12 + (iw + 2)] =
                t > 0.0f ? t : __expf(t) - 1.0f;
        }
    }
    __syncthreads();

    // 5. conv: thread = (ow, oh, ci); one ci each
    int ow = tid & 7, oh = (tid >> 3) & 7, ci = tid >> 6;
    const float* sl = slab + ci * 720;
    const float* wc = w + (size_t)(co * 8 + ci) * 125;
    float s = 0.0f;
#pragma unroll
    for (int kd = 0; kd < 5; ++kd) {
#pragma unroll
        for (int kh = 0; kh < 5; ++kh) {
            const float* row = sl + kd * 144 + (oh + kh) * 12 + ow;
            const float* wr = wc + kd * 25 + kh * 5;
#pragma unroll
            for (int kw = 0; kw < 5; ++kw) s = fmaf(row[kw], wr[kw], s);
        }
    }
    sred[tid] = s;
    __syncthreads();
    if (tid < 64) {
        float tot = bias[co];
#pragma unroll
        for (int g2 = 0; g2 < 8; ++g2) tot += sred[g2 * 64 + tid];
        yout[(size_t)(b * 8 + co) * 512 + od * 64 + tid] = tot;
        float sum = tot, sq = tot * tot;
#pragma unroll
        for (int o = 32; o > 0; o >>= 1) {
            sum += __shfl_down(sum, o, 64);
            sq  += __shfl_down(sq,  o, 64);
        }
        if (tid == 0) { atomicAdd(&stats_out[co], sum); atomicAdd(&stats_out[8 + co], sq); }
    }
}

// ---------------------------------------------------------------------------
// final BN + ELU -> d_out
// ---------------------------------------------------------------------------
__global__ __launch_bounds__(256)
void bn_final_kernel(const float* __restrict__ yin,
                     const float* __restrict__ g, const float* __restrict__ bet,
                     const float* __restrict__ stats_in, float* __restrict__ outp)
{
    int i = blockIdx.x * 256 + threadIdx.x;   // 16384 total
    float v = yin[i];                          // issue load first
    int c = (i >> 9) & 7;
    float S = stats_in[c], Q = stats_in[8 + c];
    float m  = S * (1.0f / 2048.0f);
    float vv = Q * (1.0f / 2048.0f) - m * m;
    float rs = rsqrtf(vv + 1e-5f);
    float sc = g[c] * rs;
    float sh = bet[c] - m * sc;
    float t = fmaf(v, sc, sh);
    outp[i] = t > 0.0f ? t : __expf(t) - 1.0f;
}

// ---------------------------------------------------------------------------
extern "C" void kernel_launch(void* const* d_in, const int* in_sizes, int n_in,
                              void* d_out, int out_size, void* d_ws, size_t ws_size,
                              hipStream_t stream)
{
    const float* goals       = (const float*)d_in[0];
    const float* inputs      = (const float*)d_in[1];
    const float* backgrounds = (const float*)d_in[2];
    const float* W1 = (const float*)d_in[3];
    const float* b1 = (const float*)d_in[4];
    const float* W2 = (const float*)d_in[5];
    const float* b2 = (const float*)d_in[6];
    const float* W3 = (const float*)d_in[7];
    const float* b3 = (const float*)d_in[8];
    const float* conv1_w = (const float*)d_in[9];
    const float* conv1_b = (const float*)d_in[10];
    const float* bn1_g   = (const float*)d_in[11];
    const float* bn1_b   = (const float*)d_in[12];
    const float* convs_w = (const float*)d_in[13];
    const float* convs_b = (const float*)d_in[14];
    const float* bns_g   = (const float*)d_in[15];
    const float* bns_b   = (const float*)d_in[16];

    // --- pick (K replicas, S segments) to fit the workspace -----------------
    // floats: 48*Mseg (vals) + 6*Mseg (cells u16, padded) + K*SCENE + fixed
    long ws_floats = (long)(ws_size / 4);
    long fixed = SCENE_FLOATS + 2L * 16384 + 128;
    static const int plans[][2] = {
        {42,1},{42,2},{42,4},{24,4},{21,6},{16,8},{8,12},{4,16},{2,32},{1,64}};
    int K = 1, S = 64;
    for (int pi = 0; pi < 10; ++pi) {
        int pk = plans[pi][0], ps = plans[pi][1];
        long mseg = (NPTS + ps - 1) / ps;
        long need = 54L * mseg + (long)pk * SCENE_FLOATS + fixed;
        if (need <= ws_floats) { K = pk; S = ps; break; }
    }
    int Mseg = (NPTS + S - 1) / S;

    float*          wsp     = (float*)d_ws;
    float4*         vals    = (float4*)wsp;                       // 12*Mseg float4
    unsigned short* cells   = (unsigned short*)(wsp + 48L * Mseg);// 12*Mseg u16
    float*          scenesR = wsp + 54L * Mseg;                   // K * SCENE_FLOATS
    float*          scenes  = scenesR + (size_t)K * SCENE_FLOATS; // 162000
    float*          yA      = scenes + SCENE_FLOATS;              // 16384
    float*          yB      = yA + 16384;                         // 16384
    float*          stats   = yB + 16384;                         // 7*16 floats (+pad)

    for (int s = 0; s < S; ++s) {
        int s0 = s * Mseg;
        int m  = min(Mseg, NPTS - s0);
        dim3 agrid((m + 255) / 256, B, 3);
        mlp_kernel<<<agrid, 256, 0, stream>>>(inputs, goals, backgrounds,
                                              W1, b1, W2, b2, W3, b3,
                                              vals, cells, stats, s0, m);
        dim3 bgrid(K, B, 3);
        scatter_kernel<<<bgrid, 512, 0, stream>>>(vals, cells, scenesR, K, m,
                                                  s > 0 ? 1 : 0);
    }

    reduce_kernel<<<(SCENE_FLOATS + 255) / 256, 256, 0, stream>>>(scenesR, scenes, K);

    conv1_kernel<<<256, 768, 0, stream>>>(scenes, conv1_w, conv1_b, yA, stats);

    const float* cur = yA;
    float* nxt = yB;
    for (int i = 0; i < 6; ++i) {
        const float* g   = (i == 0) ? bn1_g : (bns_g + (i - 1) * 8);
        const float* bet = (i == 0) ? bn1_b : (bns_b + (i - 1) * 8);
        conv_s_kernel<<<256, 512, 0, stream>>>(
            cur, convs_w + (size_t)i * 8000, convs_b + i * 8,
            g, bet, stats + i * 16, nxt, stats + (i + 1) * 16);
        const float* tmp = cur; cur = nxt; nxt = (float*)tmp;
    }

    bn_final_kernel<<<64, 256, 0, stream>>>(cur, bns_g + 5 * 8, bns_b + 5 * 8,
                                            stats + 6 * 16, (float*)d_out);
}